// Round 1
// baseline (2326.171 us; speedup 1.0000x reference)
//
#include <hip/hip_runtime.h>
#include <cstddef>

#define DD 512
#define DKK 64
#define SS 64
#define BB 32
#define BS 2048
#define FF 2048
#define VV 8000
#define LL 4
#define BN_SCALE 0.9995003746f
#define KSPLIT 32

// ---------------------------------------------------------------- embedding
__global__ __launch_bounds__(256) void embed_kernel(
    const int* __restrict__ seq, const float* __restrict__ emb,
    const float* __restrict__ pes, float* __restrict__ x) {
  int idx = blockIdx.x * 256 + threadIdx.x;     // BS*DD total
  int bs  = idx / DD;
  int d   = idx % DD;
  int s   = bs % SS;
  int tok = seq[bs];
  x[idx] = emb[tok * DD + d] + pes[s * DD + d];
}

// ---------------------------------------------------------------- tiled GEMM
// C[64x64 tile] = A[M,K] @ W[K,N] + bias, with epilogue:
//   EPI 0: none   EPI 1: relu   EPI 2: residual + BatchNorm (writes x)
template <int EPI>
__global__ __launch_bounds__(256) void gemm64(
    const float* __restrict__ A, int lda,
    const float* __restrict__ W, int ldw,
    const float* __restrict__ bias,
    float* __restrict__ out, int ldo, int Ktot,
    const float* __restrict__ xres,
    const float* __restrict__ gamma, const float* __restrict__ beta) {
  __shared__ float As[64][68];   // As[k][m] (transposed stage)
  __shared__ float Ws[64][68];   // Ws[k][n]
  const int t    = threadIdx.x;
  const int row0 = blockIdx.x * 64;
  const int col0 = blockIdx.y * 64;
  const int tx   = t & 15;
  const int ty   = t >> 4;
  float acc[4][4] = {};

  for (int kc = 0; kc < Ktot; kc += 64) {
#pragma unroll
    for (int j = 0; j < 4; ++j) {
      int idx = t + j * 256;          // 0..1023
      int m   = idx >> 4;             // 0..63
      int c4  = idx & 15;             // float4 slot
      float4 va = *reinterpret_cast<const float4*>(&A[(row0 + m) * lda + kc + c4 * 4]);
      As[c4 * 4 + 0][m] = va.x;
      As[c4 * 4 + 1][m] = va.y;
      As[c4 * 4 + 2][m] = va.z;
      As[c4 * 4 + 3][m] = va.w;
      float4 vw = *reinterpret_cast<const float4*>(&W[(kc + m) * ldw + col0 + c4 * 4]);
      *reinterpret_cast<float4*>(&Ws[m][c4 * 4]) = vw;
    }
    __syncthreads();
#pragma unroll
    for (int kk = 0; kk < 64; ++kk) {
      float4 a4 = *reinterpret_cast<const float4*>(&As[kk][ty * 4]);
      float4 w4 = *reinterpret_cast<const float4*>(&Ws[kk][tx * 4]);
      float av[4] = {a4.x, a4.y, a4.z, a4.w};
      float wv[4] = {w4.x, w4.y, w4.z, w4.w};
#pragma unroll
      for (int i = 0; i < 4; ++i)
#pragma unroll
        for (int j2 = 0; j2 < 4; ++j2)
          acc[i][j2] = fmaf(av[i], wv[j2], acc[i][j2]);
    }
    __syncthreads();
  }

#pragma unroll
  for (int i = 0; i < 4; ++i) {
    int r = row0 + ty * 4 + i;
#pragma unroll
    for (int j = 0; j < 4; ++j) {
      int c = col0 + tx * 4 + j;
      float v = acc[i][j] + bias[c];
      if (EPI == 1) v = v > 0.f ? v : 0.f;
      if (EPI == 2) {
        float sres = xres[r * ldo + c] + v;
        v = gamma[c] * (sres * BN_SCALE) + beta[c];
      }
      out[r * ldo + c] = v;
    }
  }
}

// ---------------------------------------------------------------- attention core
// One block per batch. Q,K,V: [B, 64, 64] fp32. 4 waves x 16 q-rows.
template <bool CAUSAL>
__global__ __launch_bounds__(256) void attn_core(
    const float* __restrict__ q, const float* __restrict__ k,
    const float* __restrict__ v, float* __restrict__ head) {
  __shared__ float Qs[64][65], Ks[64][65], Vs[64][65];
  const int b = blockIdx.x;
  const int t = threadIdx.x;
  const int base = b * SS * DKK;
#pragma unroll
  for (int j = 0; j < 16; ++j) {
    int idx = t + j * 256;         // 0..4095
    int r = idx >> 6, d = idx & 63;
    Qs[r][d] = q[base + idx];
    Ks[r][d] = k[base + idx];
    Vs[r][d] = v[base + idx];
  }
  __syncthreads();

  const int w = t >> 6;
  const int lane = t & 63;
  for (int r = 0; r < 16; ++r) {
    int qr = w * 16 + r;
    if (CAUSAL && qr == 0) {
      head[base + qr * DKK + lane] = 0.f;   // no previous tokens -> zero head
      continue;
    }
    float s = 0.f;
#pragma unroll
    for (int d = 0; d < 64; ++d) s = fmaf(Qs[qr][d], Ks[lane][d], s);
    s *= 0.125f;                            // 1/sqrt(64)
    bool valid = (!CAUSAL) || (lane < qr);
    float sm = valid ? s : -3.0e38f;
    float m = sm;
#pragma unroll
    for (int off = 32; off; off >>= 1) m = fmaxf(m, __shfl_xor(m, off));
    float p = valid ? __expf(sm - m) : 0.f;
    float sum = p;
#pragma unroll
    for (int off = 32; off; off >>= 1) sum += __shfl_xor(sum, off);
    float a = p / sum;

    float hv = 0.f;
    int jmax = CAUSAL ? qr : 64;
    for (int j2 = 0; j2 < jmax; ++j2)
      hv = fmaf(__shfl(a, j2, 64), Vs[j2][lane], hv);
    head[base + qr * DKK + lane] = hv;
  }
}

// ---------------------------------------------------------------- final GEMM
__global__ __launch_bounds__(256) void out_init(
    const float* __restrict__ out_b, float* __restrict__ out) {
  int i = blockIdx.x * 256 + threadIdx.x;   // 256000 total
  out[i] = out_b[i % VV];
}

// logits[b, col] += sum_k flat[b,k] * wout[k, col] over this block's k-range.
__global__ __launch_bounds__(256) void final_gemm(
    const float* __restrict__ flat, const float* __restrict__ wout,
    float* __restrict__ out) {
  const int col = blockIdx.x * 256 + threadIdx.x;
  if (col >= VV) return;
  const int kchunk = 32768 / KSPLIT;
  const int k0 = blockIdx.y * kchunk;
  float acc[32] = {};
  for (int k = k0; k < k0 + kchunk; k += 8) {
    float wreg[8];
#pragma unroll
    for (int j = 0; j < 8; ++j) wreg[j] = wout[(k + j) * VV + col];
#pragma unroll
    for (int b = 0; b < 32; ++b) {
      const float* fp = flat + b * 32768 + k;   // uniform address -> s_load
      float a = acc[b];
#pragma unroll
      for (int j = 0; j < 8; ++j) a = fmaf(fp[j], wreg[j], a);
      acc[b] = a;
    }
  }
#pragma unroll
  for (int b = 0; b < 32; ++b) atomicAdd(&out[b * VV + col], acc[b]);
}

// ---------------------------------------------------------------- launch
extern "C" void kernel_launch(void* const* d_in, const int* in_sizes, int n_in,
                              void* d_out, int out_size, void* d_ws, size_t ws_size,
                              hipStream_t stream) {
  const int*   seq   = (const int*)  d_in[0];
  const float* enc   = (const float*)d_in[1];
  const float* pes   = (const float*)d_in[2];
  const float* emb   = (const float*)d_in[3];
  const float* sa_wq = (const float*)d_in[4];
  const float* sa_bq = (const float*)d_in[5];
  const float* sa_wk = (const float*)d_in[6];
  const float* sa_bk = (const float*)d_in[7];
  const float* sa_wv = (const float*)d_in[8];
  const float* sa_bv = (const float*)d_in[9];
  const float* sa_wo = (const float*)d_in[10];
  const float* sa_bo = (const float*)d_in[11];
  const float* ca_wq = (const float*)d_in[12];
  const float* ca_bq = (const float*)d_in[13];
  const float* ca_wk = (const float*)d_in[14];
  const float* ca_bk = (const float*)d_in[15];
  const float* ca_wv = (const float*)d_in[16];
  const float* ca_bv = (const float*)d_in[17];
  const float* ca_wo = (const float*)d_in[18];
  const float* ca_bo = (const float*)d_in[19];
  const float* f_w1  = (const float*)d_in[20];
  const float* f_b1  = (const float*)d_in[21];
  const float* f_w2  = (const float*)d_in[22];
  const float* f_b2  = (const float*)d_in[23];
  const float* bn_g  = (const float*)d_in[24];
  const float* bn_b  = (const float*)d_in[25];
  const float* out_w = (const float*)d_in[26];
  const float* out_b = (const float*)d_in[27];
  float* out = (float*)d_out;

  float* ws = (float*)d_ws;
  float* x  = ws;                    // [BS, D]
  float* qb = x  + BS * DD;          // [BS, DK]
  float* kb = qb + BS * DKK;
  float* vb = kb + BS * DKK;
  float* hd = vb + BS * DKK;
  float* h  = hd + BS * DKK;         // [BS, FF]

  embed_kernel<<<4096, 256, 0, stream>>>(seq, emb, pes, x);

  for (int i = 0; i < LL; ++i) {
    const float* wq = sa_wq + (size_t)i * DD * DKK;
    const float* bq = sa_bq + i * DKK;
    const float* wk = sa_wk + (size_t)i * DD * DKK;
    const float* bk = sa_bk + i * DKK;
    const float* wv = sa_wv + (size_t)i * DD * DKK;
    const float* bv = sa_bv + i * DKK;
    const float* wo = sa_wo + (size_t)i * DKK * DD;
    const float* bo = sa_bo + i * DD;
    const float* g0 = bn_g + (size_t)(i * 3 + 0) * DD;
    const float* be0 = bn_b + (size_t)(i * 3 + 0) * DD;

    gemm64<0><<<dim3(32, 1), 256, 0, stream>>>(x, DD, wq, DKK, bq, qb, DKK, DD, nullptr, nullptr, nullptr);
    gemm64<0><<<dim3(32, 1), 256, 0, stream>>>(x, DD, wk, DKK, bk, kb, DKK, DD, nullptr, nullptr, nullptr);
    gemm64<0><<<dim3(32, 1), 256, 0, stream>>>(x, DD, wv, DKK, bv, vb, DKK, DD, nullptr, nullptr, nullptr);
    attn_core<true><<<32, 256, 0, stream>>>(qb, kb, vb, hd);
    gemm64<2><<<dim3(32, 8), 256, 0, stream>>>(hd, DKK, wo, DD, bo, x, DD, DKK, x, g0, be0);

    const float* cwq = ca_wq + (size_t)i * DD * DKK;
    const float* cbq = ca_bq + i * DKK;
    const float* cwk = ca_wk + (size_t)i * DD * DKK;
    const float* cbk = ca_bk + i * DKK;
    const float* cwv = ca_wv + (size_t)i * DD * DKK;
    const float* cbv = ca_bv + i * DKK;
    const float* cwo = ca_wo + (size_t)i * DKK * DD;
    const float* cbo = ca_bo + i * DD;
    const float* g1 = bn_g + (size_t)(i * 3 + 1) * DD;
    const float* be1 = bn_b + (size_t)(i * 3 + 1) * DD;

    gemm64<0><<<dim3(32, 1), 256, 0, stream>>>(x, DD, cwq, DKK, cbq, qb, DKK, DD, nullptr, nullptr, nullptr);
    gemm64<0><<<dim3(32, 1), 256, 0, stream>>>(enc, DD, cwk, DKK, cbk, kb, DKK, DD, nullptr, nullptr, nullptr);
    gemm64<0><<<dim3(32, 1), 256, 0, stream>>>(enc, DD, cwv, DKK, cbv, vb, DKK, DD, nullptr, nullptr, nullptr);
    attn_core<false><<<32, 256, 0, stream>>>(qb, kb, vb, hd);
    gemm64<2><<<dim3(32, 8), 256, 0, stream>>>(hd, DKK, cwo, DD, cbo, x, DD, DKK, x, g1, be1);

    const float* w1 = f_w1 + (size_t)i * DD * FF;
    const float* b1 = f_b1 + (size_t)i * FF;
    const float* w2 = f_w2 + (size_t)i * FF * DD;
    const float* b2 = f_b2 + (size_t)i * DD;
    const float* g2 = bn_g + (size_t)(i * 3 + 2) * DD;
    const float* be2 = bn_b + (size_t)(i * 3 + 2) * DD;

    gemm64<1><<<dim3(32, 32), 256, 0, stream>>>(x, DD, w1, FF, b1, h, FF, DD, nullptr, nullptr, nullptr);
    gemm64<2><<<dim3(32, 8), 256, 0, stream>>>(h, FF, w2, DD, b2, x, DD, FF, x, g2, be2);
  }

  out_init<<<1000, 256, 0, stream>>>(out_b, out);
  final_gemm<<<dim3(32, KSPLIT), 256, 0, stream>>>(x, out_w, out);
}

// Round 2
// 1344.435 us; speedup vs baseline: 1.7302x; 1.7302x over previous
//
#include <hip/hip_runtime.h>
#include <hip/hip_bf16.h>
#include <cstddef>

#define DD 512
#define DKK 64
#define SS 64
#define BS 2048
#define FF 2048
#define VV 8000
#define LL 4
#define BN_SCALE 0.9995003746f
#define KS2 64

typedef __attribute__((ext_vector_type(8))) short short8;
typedef __attribute__((ext_vector_type(4))) float f32x4;

// ---------------------------------------------------------------- embedding
__global__ __launch_bounds__(256) void embed_kernel(
    const int* __restrict__ seq, const float* __restrict__ emb,
    const float* __restrict__ pes, float* __restrict__ x) {
  int idx = blockIdx.x * 256 + threadIdx.x;     // BS*DD total
  int bs  = idx / DD;
  int d   = idx % DD;
  int s   = bs % SS;
  int tok = seq[bs];
  x[idx] = emb[tok * DD + d] + pes[s * DD + d];
}

// ---------------------------------------------------------------- fp32 tiled GEMM (wo projections)
// EPI 2: residual + BatchNorm (writes x fp32, optional bf16 mirror)
template <int EPI>
__global__ __launch_bounds__(256) void gemm64(
    const float* __restrict__ A, int lda,
    const float* __restrict__ W, int ldw,
    const float* __restrict__ bias,
    float* __restrict__ out, int ldo, int Ktot,
    const float* __restrict__ xres,
    const float* __restrict__ gamma, const float* __restrict__ beta,
    __hip_bfloat16* __restrict__ outb) {
  __shared__ float As[64][68];
  __shared__ float Ws[64][68];
  const int t    = threadIdx.x;
  const int row0 = blockIdx.x * 64;
  const int col0 = blockIdx.y * 64;
  const int tx   = t & 15;
  const int ty   = t >> 4;
  float acc[4][4] = {};

  for (int kc = 0; kc < Ktot; kc += 64) {
#pragma unroll
    for (int j = 0; j < 4; ++j) {
      int idx = t + j * 256;
      int m   = idx >> 4;
      int c4  = idx & 15;
      float4 va = *reinterpret_cast<const float4*>(&A[(size_t)(row0 + m) * lda + kc + c4 * 4]);
      As[c4 * 4 + 0][m] = va.x;
      As[c4 * 4 + 1][m] = va.y;
      As[c4 * 4 + 2][m] = va.z;
      As[c4 * 4 + 3][m] = va.w;
      float4 vw = *reinterpret_cast<const float4*>(&W[(size_t)(kc + m) * ldw + col0 + c4 * 4]);
      *reinterpret_cast<float4*>(&Ws[m][c4 * 4]) = vw;
    }
    __syncthreads();
#pragma unroll
    for (int kk = 0; kk < 64; ++kk) {
      float4 a4 = *reinterpret_cast<const float4*>(&As[kk][ty * 4]);
      float4 w4 = *reinterpret_cast<const float4*>(&Ws[kk][tx * 4]);
      float av[4] = {a4.x, a4.y, a4.z, a4.w};
      float wv[4] = {w4.x, w4.y, w4.z, w4.w};
#pragma unroll
      for (int i = 0; i < 4; ++i)
#pragma unroll
        for (int j2 = 0; j2 < 4; ++j2)
          acc[i][j2] = fmaf(av[i], wv[j2], acc[i][j2]);
    }
    __syncthreads();
  }

#pragma unroll
  for (int i = 0; i < 4; ++i) {
    int r = row0 + ty * 4 + i;
#pragma unroll
    for (int j = 0; j < 4; ++j) {
      int c = col0 + tx * 4 + j;
      float v = acc[i][j] + bias[c];
      if (EPI == 2) {
        float sres = xres[(size_t)r * ldo + c] + v;
        v = gamma[c] * (sres * BN_SCALE) + beta[c];
      }
      out[(size_t)r * ldo + c] = v;
      if (EPI == 2 && outb) outb[(size_t)r * ldo + c] = __float2bfloat16(v);
    }
  }
}

// ---------------------------------------------------------------- fused q/k/v projections
__global__ __launch_bounds__(256) void gemm_qkv(
    const float* __restrict__ Aq, const float* __restrict__ Akv,
    const float* __restrict__ Wq, const float* __restrict__ Wk, const float* __restrict__ Wv,
    const float* __restrict__ bqv, const float* __restrict__ bkv, const float* __restrict__ bvv,
    float* __restrict__ oq, float* __restrict__ ok, float* __restrict__ ov) {
  const int z = blockIdx.y;
  const float* A    = (z == 0) ? Aq  : Akv;
  const float* W    = (z == 0) ? Wq  : (z == 1) ? Wk : Wv;
  const float* bias = (z == 0) ? bqv : (z == 1) ? bkv : bvv;
  float* o          = (z == 0) ? oq  : (z == 1) ? ok : ov;

  __shared__ float As[64][68];
  __shared__ float Ws[64][68];
  const int t    = threadIdx.x;
  const int row0 = blockIdx.x * 64;
  const int tx   = t & 15;
  const int ty   = t >> 4;
  float acc[4][4] = {};

  for (int kc = 0; kc < DD; kc += 64) {
#pragma unroll
    for (int j = 0; j < 4; ++j) {
      int idx = t + j * 256;
      int m   = idx >> 4;
      int c4  = idx & 15;
      float4 va = *reinterpret_cast<const float4*>(&A[(size_t)(row0 + m) * DD + kc + c4 * 4]);
      As[c4 * 4 + 0][m] = va.x;
      As[c4 * 4 + 1][m] = va.y;
      As[c4 * 4 + 2][m] = va.z;
      As[c4 * 4 + 3][m] = va.w;
      float4 vw = *reinterpret_cast<const float4*>(&W[(size_t)(kc + m) * DKK + c4 * 4]);
      *reinterpret_cast<float4*>(&Ws[m][c4 * 4]) = vw;
    }
    __syncthreads();
#pragma unroll
    for (int kk = 0; kk < 64; ++kk) {
      float4 a4 = *reinterpret_cast<const float4*>(&As[kk][ty * 4]);
      float4 w4 = *reinterpret_cast<const float4*>(&Ws[kk][tx * 4]);
      float av[4] = {a4.x, a4.y, a4.z, a4.w};
      float wv[4] = {w4.x, w4.y, w4.z, w4.w};
#pragma unroll
      for (int i = 0; i < 4; ++i)
#pragma unroll
        for (int j2 = 0; j2 < 4; ++j2)
          acc[i][j2] = fmaf(av[i], wv[j2], acc[i][j2]);
    }
    __syncthreads();
  }

#pragma unroll
  for (int i = 0; i < 4; ++i) {
    int r = row0 + ty * 4 + i;
#pragma unroll
    for (int j = 0; j < 4; ++j) {
      int c = tx * 4 + j;
      o[(size_t)r * DKK + c] = acc[i][j] + bias[c];
    }
  }
}

// ---------------------------------------------------------------- attention core
template <bool CAUSAL>
__global__ __launch_bounds__(256) void attn_core(
    const float* __restrict__ q, const float* __restrict__ k,
    const float* __restrict__ v, float* __restrict__ head) {
  __shared__ float Qs[64][65], Ks[64][65], Vs[64][65];
  const int b = blockIdx.x;
  const int t = threadIdx.x;
  const int base = b * SS * DKK;
#pragma unroll
  for (int j = 0; j < 16; ++j) {
    int idx = t + j * 256;
    int r = idx >> 6, d = idx & 63;
    Qs[r][d] = q[base + idx];
    Ks[r][d] = k[base + idx];
    Vs[r][d] = v[base + idx];
  }
  __syncthreads();

  const int w = t >> 6;
  const int lane = t & 63;
  for (int r = 0; r < 16; ++r) {
    int qr = w * 16 + r;
    if (CAUSAL && qr == 0) {
      head[base + qr * DKK + lane] = 0.f;
      continue;
    }
    float s = 0.f;
#pragma unroll
    for (int d = 0; d < 64; ++d) s = fmaf(Qs[qr][d], Ks[lane][d], s);
    s *= 0.125f;
    bool valid = (!CAUSAL) || (lane < qr);
    float sm = valid ? s : -3.0e38f;
    float m = sm;
#pragma unroll
    for (int off = 32; off; off >>= 1) m = fmaxf(m, __shfl_xor(m, off));
    float p = valid ? __expf(sm - m) : 0.f;
    float sum = p;
#pragma unroll
    for (int off = 32; off; off >>= 1) sum += __shfl_xor(sum, off);
    float a = p / sum;

    float hv = 0.f;
    int jmax = CAUSAL ? qr : 64;
    for (int j2 = 0; j2 < jmax; ++j2)
      hv = fmaf(__shfl(a, j2, 64), Vs[j2][lane], hv);
    head[base + qr * DKK + lane] = hv;
  }
}

// ---------------------------------------------------------------- weight transpose+convert (fp32 [K,N] -> bf16 [N,K]), grid.z = layer
__global__ __launch_bounds__(256) void convT(
    const float* __restrict__ w, __hip_bfloat16* __restrict__ o, int K, int N) {
  __shared__ float t[32][33];
  const float* wl = w + (size_t)blockIdx.z * K * N;
  __hip_bfloat16* ol = o + (size_t)blockIdx.z * K * N;
  int n0 = blockIdx.x * 32, k0 = blockIdx.y * 32;
  int tx = threadIdx.x & 31, ty = threadIdx.x >> 5;   // ty 0..7
#pragma unroll
  for (int p = 0; p < 4; ++p)
    t[ty + p * 8][tx] = wl[(size_t)(k0 + ty + p * 8) * N + n0 + tx];
  __syncthreads();
#pragma unroll
  for (int p = 0; p < 4; ++p)
    ol[(size_t)(n0 + ty + p * 8) * K + k0 + tx] = __float2bfloat16(t[tx][ty + p * 8]);
}

// ---------------------------------------------------------------- bf16 MFMA GEMM, 128x128 tile, BK=64
// A [M,K] bf16 row-major; BT [N,K] bf16 row-major (i.e. B transposed)
// EPI 1: bias+relu -> bf16 out ; EPI 2: bias + residual + BN -> fp32 out
template <int EPI>
__global__ __launch_bounds__(256) void mm_bf16(
    const __hip_bfloat16* __restrict__ A, const __hip_bfloat16* __restrict__ BT,
    int K, int N, const float* __restrict__ bias,
    __hip_bfloat16* __restrict__ outb, float* __restrict__ outf,
    const float* __restrict__ xres,
    const float* __restrict__ gamma, const float* __restrict__ beta) {
  __shared__ __align__(16) __hip_bfloat16 As[128 * 64];
  __shared__ __align__(16) __hip_bfloat16 Bs[128 * 64];
  const int tid  = threadIdx.x;
  const int lane = tid & 63;
  const int w    = tid >> 6;
  const int wr   = w >> 1, wc = w & 1;
  const int row0 = blockIdx.x * 128, col0 = blockIdx.y * 128;
  f32x4 acc[4][4] = {};

  const int l15 = lane & 15;
  const int lhi = lane >> 4;          // 0..3

  for (int kc = 0; kc < K; kc += 64) {
    short8 ra[4], rb[4];
#pragma unroll
    for (int c = 0; c < 4; ++c) {
      int j  = c * 256 + tid;         // 0..1023
      int r  = j >> 3;                // 0..127
      int c8 = j & 7;
      ra[c] = *(const short8*)(A  + (size_t)(row0 + r) * K + kc + c8 * 8);
      rb[c] = *(const short8*)(BT + (size_t)(col0 + r) * K + kc + c8 * 8);
    }
    __syncthreads();                  // prev tile's reads done
#pragma unroll
    for (int c = 0; c < 4; ++c) {
      int j = c * 256 + tid;
      *(short8*)(As + j * 8) = ra[c];
      *(short8*)(Bs + j * 8) = rb[c];
    }
    __syncthreads();
#pragma unroll
    for (int kk = 0; kk < 2; ++kk) {
      short8 af[4], bfm[4];
#pragma unroll
      for (int f = 0; f < 4; ++f) {
        af[f]  = *(const short8*)(As + (wr * 64 + f * 16 + l15) * 64 + kk * 32 + lhi * 8);
        bfm[f] = *(const short8*)(Bs + (wc * 64 + f * 16 + l15) * 64 + kk * 32 + lhi * 8);
      }
#pragma unroll
      for (int fm = 0; fm < 4; ++fm)
#pragma unroll
        for (int fn = 0; fn < 4; ++fn)
          acc[fm][fn] = __builtin_amdgcn_mfma_f32_16x16x32_bf16(af[fm], bfm[fn], acc[fm][fn], 0, 0, 0);
    }
  }

#pragma unroll
  for (int fm = 0; fm < 4; ++fm)
#pragma unroll
    for (int r = 0; r < 4; ++r) {
      int row = row0 + wr * 64 + fm * 16 + lhi * 4 + r;
#pragma unroll
      for (int fn = 0; fn < 4; ++fn) {
        int col = col0 + wc * 64 + fn * 16 + l15;
        float v = acc[fm][fn][r] + bias[col];
        if (EPI == 1) {
          v = v > 0.f ? v : 0.f;
          outb[(size_t)row * N + col] = __float2bfloat16(v);
        } else {
          float sres = xres[(size_t)row * N + col] + v;
          outf[(size_t)row * N + col] = gamma[col] * (sres * BN_SCALE) + beta[col];
        }
      }
    }
}

// ---------------------------------------------------------------- final GEMM
__global__ __launch_bounds__(256) void out_init(
    const float* __restrict__ out_b, float* __restrict__ out) {
  int i = blockIdx.x * 256 + threadIdx.x;   // 256000 total
  out[i] = out_b[i % VV];
}

// out[b, 4c..4c+3] += sum over this block's 512-row k-chunk
__global__ __launch_bounds__(256) void final_gemm2(
    const float* __restrict__ flat, const float* __restrict__ wout,
    float* __restrict__ out) {
  int c4 = blockIdx.x * 256 + threadIdx.x;         // 0..2047
  const bool act = c4 < 2000;
  if (!act) c4 = 1999;
  const int k0 = blockIdx.y * 512;
  const float* Wp = wout + (size_t)k0 * VV + c4 * 4;
  f32x4 acc[32] = {};
  for (int k = 0; k < 512; k += 4) {
    f32x4 w0 = *(const f32x4*)(Wp + (size_t)(k + 0) * VV);
    f32x4 w1 = *(const f32x4*)(Wp + (size_t)(k + 1) * VV);
    f32x4 w2 = *(const f32x4*)(Wp + (size_t)(k + 2) * VV);
    f32x4 w3 = *(const f32x4*)(Wp + (size_t)(k + 3) * VV);
#pragma unroll
    for (int bh = 0; bh < 2; ++bh) {
      f32x4 f[16];
#pragma unroll
      for (int b = 0; b < 16; ++b)
        f[b] = *(const f32x4*)(flat + (size_t)(bh * 16 + b) * (SS * DD) + k0 + k);
#pragma unroll
      for (int b = 0; b < 16; ++b) {
        int bb = bh * 16 + b;
        acc[bb] = acc[bb] + f[b].x * w0 + f[b].y * w1 + f[b].z * w2 + f[b].w * w3;
      }
    }
  }
  if (act) {
#pragma unroll
    for (int b = 0; b < 32; ++b) {
      float* op = out + (size_t)b * VV + c4 * 4;
      atomicAdd(op + 0, acc[b].x);
      atomicAdd(op + 1, acc[b].y);
      atomicAdd(op + 2, acc[b].z);
      atomicAdd(op + 3, acc[b].w);
    }
  }
}

// ---------------------------------------------------------------- launch
extern "C" void kernel_launch(void* const* d_in, const int* in_sizes, int n_in,
                              void* d_out, int out_size, void* d_ws, size_t ws_size,
                              hipStream_t stream) {
  const int*   seq   = (const int*)  d_in[0];
  const float* enc   = (const float*)d_in[1];
  const float* pes   = (const float*)d_in[2];
  const float* emb   = (const float*)d_in[3];
  const float* sa_wq = (const float*)d_in[4];
  const float* sa_bq = (const float*)d_in[5];
  const float* sa_wk = (const float*)d_in[6];
  const float* sa_bk = (const float*)d_in[7];
  const float* sa_wv = (const float*)d_in[8];
  const float* sa_bv = (const float*)d_in[9];
  const float* sa_wo = (const float*)d_in[10];
  const float* sa_bo = (const float*)d_in[11];
  const float* ca_wq = (const float*)d_in[12];
  const float* ca_bq = (const float*)d_in[13];
  const float* ca_wk = (const float*)d_in[14];
  const float* ca_bk = (const float*)d_in[15];
  const float* ca_wv = (const float*)d_in[16];
  const float* ca_bv = (const float*)d_in[17];
  const float* ca_wo = (const float*)d_in[18];
  const float* ca_bo = (const float*)d_in[19];
  const float* f_w1  = (const float*)d_in[20];
  const float* f_b1  = (const float*)d_in[21];
  const float* f_w2  = (const float*)d_in[22];
  const float* f_b2  = (const float*)d_in[23];
  const float* bn_g  = (const float*)d_in[24];
  const float* bn_b  = (const float*)d_in[25];
  const float* out_w = (const float*)d_in[26];
  const float* out_b = (const float*)d_in[27];
  float* out = (float*)d_out;

  float* ws = (float*)d_ws;
  float* x  = ws;                          // [BS, D] fp32
  float* qb = x  + (size_t)BS * DD;
  float* kb = qb + (size_t)BS * DKK;
  float* vb = kb + (size_t)BS * DKK;
  float* hd = vb + (size_t)BS * DKK;
  __hip_bfloat16* xb  = (__hip_bfloat16*)(hd + (size_t)BS * DKK);  // [BS, D] bf16
  __hip_bfloat16* h   = xb  + (size_t)BS * DD;                     // [BS, FF] bf16
  __hip_bfloat16* w1T = h   + (size_t)BS * FF;                     // [L][FF][D] bf16
  __hip_bfloat16* w2T = w1T + (size_t)LL * FF * DD;                // [L][D][FF] bf16

  // weight transpose+convert (per call; deterministic)
  convT<<<dim3(FF / 32, DD / 32, LL), 256, 0, stream>>>(f_w1, w1T, DD, FF);
  convT<<<dim3(DD / 32, FF / 32, LL), 256, 0, stream>>>(f_w2, w2T, FF, DD);

  embed_kernel<<<4096, 256, 0, stream>>>(seq, emb, pes, x);

  for (int i = 0; i < LL; ++i) {
    const float* g0  = bn_g + (size_t)(i * 3 + 0) * DD;
    const float* be0 = bn_b + (size_t)(i * 3 + 0) * DD;
    const float* g1  = bn_g + (size_t)(i * 3 + 1) * DD;
    const float* be1 = bn_b + (size_t)(i * 3 + 1) * DD;
    const float* g2  = bn_g + (size_t)(i * 3 + 2) * DD;
    const float* be2 = bn_b + (size_t)(i * 3 + 2) * DD;

    // ---- self-attention
    gemm_qkv<<<dim3(32, 3), 256, 0, stream>>>(
        x, x,
        sa_wq + (size_t)i * DD * DKK, sa_wk + (size_t)i * DD * DKK, sa_wv + (size_t)i * DD * DKK,
        sa_bq + i * DKK, sa_bk + i * DKK, sa_bv + i * DKK,
        qb, kb, vb);
    attn_core<true><<<32, 256, 0, stream>>>(qb, kb, vb, hd);
    gemm64<2><<<dim3(32, 8), 256, 0, stream>>>(
        hd, DKK, sa_wo + (size_t)i * DKK * DD, DD, sa_bo + i * DD,
        x, DD, DKK, x, g0, be0, nullptr);

    // ---- cross-attention
    gemm_qkv<<<dim3(32, 3), 256, 0, stream>>>(
        x, enc,
        ca_wq + (size_t)i * DD * DKK, ca_wk + (size_t)i * DD * DKK, ca_wv + (size_t)i * DD * DKK,
        ca_bq + i * DKK, ca_bk + i * DKK, ca_bv + i * DKK,
        qb, kb, vb);
    attn_core<false><<<32, 256, 0, stream>>>(qb, kb, vb, hd);
    gemm64<2><<<dim3(32, 8), 256, 0, stream>>>(
        hd, DKK, ca_wo + (size_t)i * DKK * DD, DD, ca_bo + i * DD,
        x, DD, DKK, x, g1, be1, xb);   // bf16 mirror feeds FFN w1

    // ---- FFN (bf16 MFMA)
    mm_bf16<1><<<dim3(16, 16), 256, 0, stream>>>(
        xb, w1T + (size_t)i * FF * DD, DD, FF, f_b1 + (size_t)i * FF,
        h, nullptr, nullptr, nullptr, nullptr);
    mm_bf16<2><<<dim3(16, 4), 256, 0, stream>>>(
        h, w2T + (size_t)i * DD * FF, FF, DD, f_b2 + (size_t)i * DD,
        nullptr, x, x, g2, be2);
  }

  out_init<<<1000, 256, 0, stream>>>(out_b, out);
  final_gemm2<<<dim3(8, KS2), 256, 0, stream>>>(x, out_w, out);
}

// Round 3
// 727.985 us; speedup vs baseline: 3.1954x; 1.8468x over previous
//
#include <hip/hip_runtime.h>
#include <hip/hip_bf16.h>
#include <cstddef>

#define DD 512
#define DKK 64
#define SS 64
#define BS 2048
#define FF 2048
#define VV 8000
#define LL 4
#define BN_SCALE 0.9995003746f

typedef __attribute__((ext_vector_type(8))) short short8;
typedef __attribute__((ext_vector_type(4))) float f32x4;

// ---------------------------------------------------------------- embedding (fp32 + bf16 mirror)
__global__ __launch_bounds__(256) void embed_kernel(
    const int* __restrict__ seq, const float* __restrict__ emb,
    const float* __restrict__ pes, float* __restrict__ x,
    __hip_bfloat16* __restrict__ xb) {
  int idx = blockIdx.x * 256 + threadIdx.x;     // BS*DD total
  int bs  = idx / DD;
  int d   = idx % DD;
  int s   = bs % SS;
  int tok = seq[bs];
  float v = emb[tok * DD + d] + pes[s * DD + d];
  x[idx]  = v;
  xb[idx] = __float2bfloat16(v);
}

// ---------------------------------------------------------------- fp32 -> bf16 elementwise
__global__ __launch_bounds__(256) void tobf16(
    const float* __restrict__ in, __hip_bfloat16* __restrict__ o) {
  int i = blockIdx.x * 256 + threadIdx.x;
  o[i] = __float2bfloat16(in[i]);
}

// ---------------------------------------------------------------- weight transpose+convert
// src: fp32 [K][N] (per layer K*N). dst: bf16 rows n -> [n][K] at dst + z*oLS + oRowOff*K
__global__ __launch_bounds__(256) void convT(
    const float* __restrict__ w, __hip_bfloat16* __restrict__ o,
    int K, int N, int oLS, int oRowOff) {
  __shared__ float t[32][33];
  const float* wl = w + (size_t)blockIdx.z * K * N;
  __hip_bfloat16* ol = o + (size_t)blockIdx.z * oLS + (size_t)oRowOff * K;
  int n0 = blockIdx.x * 32, k0 = blockIdx.y * 32;
  int tx = threadIdx.x & 31, ty = threadIdx.x >> 5;   // ty 0..7
#pragma unroll
  for (int p = 0; p < 4; ++p)
    t[ty + p * 8][tx] = wl[(size_t)(k0 + ty + p * 8) * N + n0 + tx];
  __syncthreads();
#pragma unroll
  for (int p = 0; p < 4; ++p)
    ol[(size_t)(n0 + ty + p * 8) * K + k0 + tx] = __float2bfloat16(t[tx][ty + p * 8]);
}

// ---------------------------------------------------------------- fused attention block
// grid (4 col-chunks of 128, 32 batches), 256 threads (4 waves)
// qkvT: [192][512] bf16 (rows 0-63 Wq^T, 64-127 Wk^T, 128-191 Wv^T); woT: [512][64] bf16
template <bool CAUSAL>
__global__ __launch_bounds__(256) void fused_attn(
    const __hip_bfloat16* __restrict__ qin,
    const __hip_bfloat16* __restrict__ kvin,
    const __hip_bfloat16* __restrict__ qkvT,
    const float* __restrict__ bq, const float* __restrict__ bk, const float* __restrict__ bv,
    const __hip_bfloat16* __restrict__ woT,
    const float* __restrict__ bo,
    const float* __restrict__ xres,
    const float* __restrict__ gamma, const float* __restrict__ beta,
    float* __restrict__ xout, __hip_bfloat16* __restrict__ xbout) {
  __shared__ __hip_bfloat16 Ws[192][72];                    // weight k-chunk, padded
  __shared__ __hip_bfloat16 Qb[64][72], Kb[64][72], Vt[64][72], Pb[64][72], Hb[64][72];
  const int tid  = threadIdx.x;
  const int w    = tid >> 6;
  const int lane = tid & 63;
  const int l15  = lane & 15, lhi = lane >> 4;
  const int b    = blockIdx.y;
  const int col0 = blockIdx.x * 128;
  const size_t abase = (size_t)(b * SS) * DD;

  // ---- phase A: Q,K,V = [X | Xkv] @ Wqkv  (A-frags straight from global bf16)
  f32x4 acc[12] = {};
  for (int kc = 0; kc < DD; kc += 64) {
    __syncthreads();
#pragma unroll
    for (int u = 0; u < 6; ++u) {
      int idx = u * 256 + tid; int row = idx >> 3; int c8 = idx & 7;
      *(short8*)&Ws[row][c8 * 8] = *(const short8*)(qkvT + (size_t)row * DD + kc + c8 * 8);
    }
    __syncthreads();
#pragma unroll
    for (int kk = 0; kk < 2; ++kk) {
      short8 aq  = *(const short8*)(qin  + abase + (size_t)(w * 16 + l15) * DD + kc + kk * 32 + lhi * 8);
      short8 akv = *(const short8*)(kvin + abase + (size_t)(w * 16 + l15) * DD + kc + kk * 32 + lhi * 8);
#pragma unroll
      for (int f = 0; f < 12; ++f) {
        short8 bfr = *(const short8*)&Ws[f * 16 + l15][kk * 32 + lhi * 8];
        acc[f] = __builtin_amdgcn_mfma_f32_16x16x32_bf16(f < 4 ? aq : akv, bfr, acc[f], 0, 0, 0);
      }
    }
  }
  // C-layout: col=(f&3)*16+l15, row=w*16+lhi*4+r   (Q scaled by 1/8 here)
#pragma unroll
  for (int f = 0; f < 12; ++f) {
    int c = (f & 3) * 16 + l15;
#pragma unroll
    for (int r = 0; r < 4; ++r) {
      int row = w * 16 + lhi * 4 + r;
      if (f < 4)      Qb[row][c] = __float2bfloat16((acc[f][r] + bq[c]) * 0.125f);
      else if (f < 8) Kb[row][c] = __float2bfloat16(acc[f][r] + bk[c]);
      else            Vt[c][row] = __float2bfloat16(acc[f][r] + bv[c]);   // transposed for PV B-operand
    }
  }
  __syncthreads();

  // ---- phase B: S = Q @ K^T  (wave w owns rows w*16..+15)
  f32x4 sacc[4] = {};
#pragma unroll
  for (int kk = 0; kk < 2; ++kk) {
    short8 aq = *(const short8*)&Qb[w * 16 + l15][kk * 32 + lhi * 8];
#pragma unroll
    for (int f = 0; f < 4; ++f) {
      short8 bfr = *(const short8*)&Kb[f * 16 + l15][kk * 32 + lhi * 8];
      sacc[f] = __builtin_amdgcn_mfma_f32_16x16x32_bf16(aq, bfr, sacc[f], 0, 0, 0);
    }
  }
  // softmax per row; row's 64 values live in 16 lanes (same lhi) x 4 frags
#pragma unroll
  for (int r = 0; r < 4; ++r) {
    int qr = w * 16 + lhi * 4 + r;
    float sv[4];
    float m = -3.0e38f;
#pragma unroll
    for (int f = 0; f < 4; ++f) {
      int kt = f * 16 + l15;
      bool valid = (!CAUSAL) || (kt < qr);
      sv[f] = valid ? sacc[f][r] : -3.0e38f;
      m = fmaxf(m, sv[f]);
    }
#pragma unroll
    for (int off = 1; off < 16; off <<= 1) m = fmaxf(m, __shfl_xor(m, off));
    float pv[4], sum = 0.f;
#pragma unroll
    for (int f = 0; f < 4; ++f) {
      pv[f] = (sv[f] > -1.0e38f) ? __expf(sv[f] - m) : 0.f;
      sum += pv[f];
    }
#pragma unroll
    for (int off = 1; off < 16; off <<= 1) sum += __shfl_xor(sum, off);
    float rs = sum > 0.f ? 1.f / sum : 0.f;                 // qr==0 causal row -> all zero
#pragma unroll
    for (int f = 0; f < 4; ++f)
      Pb[qr][f * 16 + l15] = __float2bfloat16(pv[f] * rs);
  }
  __syncthreads();

  // ---- phase C: head = P @ V
  f32x4 hacc[4] = {};
#pragma unroll
  for (int kk = 0; kk < 2; ++kk) {
    short8 ap = *(const short8*)&Pb[w * 16 + l15][kk * 32 + lhi * 8];
#pragma unroll
    for (int f = 0; f < 4; ++f) {
      short8 bfr = *(const short8*)&Vt[f * 16 + l15][kk * 32 + lhi * 8];
      hacc[f] = __builtin_amdgcn_mfma_f32_16x16x32_bf16(ap, bfr, hacc[f], 0, 0, 0);
    }
  }
#pragma unroll
  for (int f = 0; f < 4; ++f)
#pragma unroll
    for (int r = 0; r < 4; ++r)
      Hb[w * 16 + lhi * 4 + r][f * 16 + l15] = __float2bfloat16(hacc[f][r]);
  __syncthreads();

  // ---- phase D: out = head @ Wo (this block's 128 cols) + bo, +residual, BN
  f32x4 oacc[8] = {};
#pragma unroll
  for (int kk = 0; kk < 2; ++kk) {
    short8 ah = *(const short8*)&Hb[w * 16 + l15][kk * 32 + lhi * 8];
#pragma unroll
    for (int f = 0; f < 8; ++f) {
      short8 bfr = *(const short8*)(woT + (size_t)(col0 + f * 16 + l15) * DKK + kk * 32 + lhi * 8);
      oacc[f] = __builtin_amdgcn_mfma_f32_16x16x32_bf16(ah, bfr, oacc[f], 0, 0, 0);
    }
  }
#pragma unroll
  for (int f = 0; f < 8; ++f) {
    int c = col0 + f * 16 + l15;
    float g = gamma[c], be = beta[c], bb = bo[c];
#pragma unroll
    for (int r = 0; r < 4; ++r) {
      int row = b * SS + w * 16 + lhi * 4 + r;
      float v = oacc[f][r] + bb;
      float res = xres[(size_t)row * DD + c] + v;
      float y = g * (res * BN_SCALE) + be;
      xout[(size_t)row * DD + c]  = y;
      xbout[(size_t)row * DD + c] = __float2bfloat16(y);
    }
  }
}

// ---------------------------------------------------------------- bf16 MFMA GEMM, 128x128 tile, BK=64
// EPI 1: bias+relu -> bf16 ; EPI 2: bias+residual+BN -> fp32 + bf16 mirror
template <int EPI>
__global__ __launch_bounds__(256) void mm_bf16(
    const __hip_bfloat16* __restrict__ A, const __hip_bfloat16* __restrict__ BT,
    int K, int N, const float* __restrict__ bias,
    __hip_bfloat16* __restrict__ outb, float* __restrict__ outf,
    const float* __restrict__ xres,
    const float* __restrict__ gamma, const float* __restrict__ beta) {
  __shared__ __align__(16) __hip_bfloat16 As[128 * 64];
  __shared__ __align__(16) __hip_bfloat16 Bs[128 * 64];
  const int tid  = threadIdx.x;
  const int lane = tid & 63;
  const int w    = tid >> 6;
  const int wr   = w >> 1, wc = w & 1;
  const int row0 = blockIdx.x * 128, col0 = blockIdx.y * 128;
  f32x4 acc[4][4] = {};

  const int l15 = lane & 15;
  const int lhi = lane >> 4;

  for (int kc = 0; kc < K; kc += 64) {
    short8 ra[4], rb[4];
#pragma unroll
    for (int c = 0; c < 4; ++c) {
      int j  = c * 256 + tid;
      int r  = j >> 3;
      int c8 = j & 7;
      ra[c] = *(const short8*)(A  + (size_t)(row0 + r) * K + kc + c8 * 8);
      rb[c] = *(const short8*)(BT + (size_t)(col0 + r) * K + kc + c8 * 8);
    }
    __syncthreads();
#pragma unroll
    for (int c = 0; c < 4; ++c) {
      int j = c * 256 + tid;
      *(short8*)(As + j * 8) = ra[c];
      *(short8*)(Bs + j * 8) = rb[c];
    }
    __syncthreads();
#pragma unroll
    for (int kk = 0; kk < 2; ++kk) {
      short8 af[4], bfm[4];
#pragma unroll
      for (int f = 0; f < 4; ++f) {
        af[f]  = *(const short8*)(As + (wr * 64 + f * 16 + l15) * 64 + kk * 32 + lhi * 8);
        bfm[f] = *(const short8*)(Bs + (wc * 64 + f * 16 + l15) * 64 + kk * 32 + lhi * 8);
      }
#pragma unroll
      for (int fm = 0; fm < 4; ++fm)
#pragma unroll
        for (int fn = 0; fn < 4; ++fn)
          acc[fm][fn] = __builtin_amdgcn_mfma_f32_16x16x32_bf16(af[fm], bfm[fn], acc[fm][fn], 0, 0, 0);
    }
  }

#pragma unroll
  for (int fm = 0; fm < 4; ++fm)
#pragma unroll
    for (int r = 0; r < 4; ++r) {
      int row = row0 + wr * 64 + fm * 16 + lhi * 4 + r;
#pragma unroll
      for (int fn = 0; fn < 4; ++fn) {
        int col = col0 + wc * 64 + fn * 16 + l15;
        float v = acc[fm][fn][r] + bias[col];
        if (EPI == 1) {
          v = v > 0.f ? v : 0.f;
          outb[(size_t)row * N + col] = __float2bfloat16(v);
        } else {
          float sres = xres[(size_t)row * N + col] + v;
          float y = gamma[col] * (sres * BN_SCALE) + beta[col];
          outf[(size_t)row * N + col] = y;
          outb[(size_t)row * N + col] = __float2bfloat16(y);
        }
      }
    }
}

// ---------------------------------------------------------------- final GEMM: split-K partials (atomic-free)
__global__ __launch_bounds__(256) void fgemm_part(
    const float* __restrict__ flat, const float* __restrict__ wout,
    float* __restrict__ fpart, int kchunk) {
  int c4 = blockIdx.x * 256 + threadIdx.x;         // 0..2047 (cols c4*4..+3)
  const bool act = c4 < 2000;
  const int c4c = act ? c4 : 1999;
  const int k0 = blockIdx.y * kchunk;
  const float* Wp = wout + (size_t)k0 * VV + (size_t)c4c * 4;
  f32x4 acc[32] = {};
  for (int k = 0; k < kchunk; k += 4) {
    f32x4 w0 = *(const f32x4*)(Wp + (size_t)(k + 0) * VV);
    f32x4 w1 = *(const f32x4*)(Wp + (size_t)(k + 1) * VV);
    f32x4 w2 = *(const f32x4*)(Wp + (size_t)(k + 2) * VV);
    f32x4 w3 = *(const f32x4*)(Wp + (size_t)(k + 3) * VV);
#pragma unroll
    for (int bh = 0; bh < 2; ++bh) {
      f32x4 f[16];
#pragma unroll
      for (int b = 0; b < 16; ++b)
        f[b] = *(const f32x4*)(flat + (size_t)(bh * 16 + b) * (SS * DD) + k0 + k);
#pragma unroll
      for (int b = 0; b < 16; ++b) {
        int bb = bh * 16 + b;
        acc[bb] = acc[bb] + f[b].x * w0 + f[b].y * w1 + f[b].z * w2 + f[b].w * w3;
      }
    }
  }
  if (act) {
    float* pp = fpart + (size_t)blockIdx.y * 32 * 8192 + (size_t)c4 * 4;
#pragma unroll
    for (int b = 0; b < 32; ++b)
      *(f32x4*)(pp + (size_t)b * 8192) = acc[b];
  }
}

__global__ __launch_bounds__(256) void freduce(
    const float* __restrict__ fpart, const float* __restrict__ out_b,
    float* __restrict__ out, int KS) {
  int i = blockIdx.x * 256 + threadIdx.x;          // 256000 total
  int b = i / VV, c = i % VV;
  float s = out_b[c];
  for (int ks = 0; ks < KS; ++ks)
    s += fpart[((size_t)ks * 32 + b) * 8192 + c];
  out[i] = s;
}

// ---------------------------------------------------------------- launch
extern "C" void kernel_launch(void* const* d_in, const int* in_sizes, int n_in,
                              void* d_out, int out_size, void* d_ws, size_t ws_size,
                              hipStream_t stream) {
  const int*   seq   = (const int*)  d_in[0];
  const float* enc   = (const float*)d_in[1];
  const float* pes   = (const float*)d_in[2];
  const float* emb   = (const float*)d_in[3];
  const float* sa_wq = (const float*)d_in[4];
  const float* sa_bq = (const float*)d_in[5];
  const float* sa_wk = (const float*)d_in[6];
  const float* sa_bk = (const float*)d_in[7];
  const float* sa_wv = (const float*)d_in[8];
  const float* sa_bv = (const float*)d_in[9];
  const float* sa_wo = (const float*)d_in[10];
  const float* sa_bo = (const float*)d_in[11];
  const float* ca_wq = (const float*)d_in[12];
  const float* ca_bq = (const float*)d_in[13];
  const float* ca_wk = (const float*)d_in[14];
  const float* ca_bk = (const float*)d_in[15];
  const float* ca_wv = (const float*)d_in[16];
  const float* ca_bv = (const float*)d_in[17];
  const float* ca_wo = (const float*)d_in[18];
  const float* ca_bo = (const float*)d_in[19];
  const float* f_w1  = (const float*)d_in[20];
  const float* f_b1  = (const float*)d_in[21];
  const float* f_w2  = (const float*)d_in[22];
  const float* f_b2  = (const float*)d_in[23];
  const float* bn_g  = (const float*)d_in[24];
  const float* bn_b  = (const float*)d_in[25];
  const float* out_w = (const float*)d_in[26];
  const float* out_b = (const float*)d_in[27];
  float* out = (float*)d_out;

  // ---- ws carve-up
  char* wp = (char*)d_ws;
  size_t off = 0;
  auto alloc = [&](size_t bytes) { void* p = wp + off; off += (bytes + 255) & ~(size_t)255; return p; };
  float* x0 = (float*)alloc((size_t)BS * DD * 4);
  float* x1 = (float*)alloc((size_t)BS * DD * 4);
  __hip_bfloat16* xb0 = (__hip_bfloat16*)alloc((size_t)BS * DD * 2);
  __hip_bfloat16* xb1 = (__hip_bfloat16*)alloc((size_t)BS * DD * 2);
  __hip_bfloat16* h   = (__hip_bfloat16*)alloc((size_t)BS * FF * 2);
  __hip_bfloat16* w1T = (__hip_bfloat16*)alloc((size_t)LL * DD * FF * 2);
  __hip_bfloat16* w2T = (__hip_bfloat16*)alloc((size_t)LL * DD * FF * 2);
  __hip_bfloat16* qkvTs = (__hip_bfloat16*)alloc((size_t)LL * 192 * DD * 2);
  __hip_bfloat16* qkvTc = (__hip_bfloat16*)alloc((size_t)LL * 192 * DD * 2);
  __hip_bfloat16* woTs  = (__hip_bfloat16*)alloc((size_t)LL * DD * DKK * 2);
  __hip_bfloat16* woTc  = (__hip_bfloat16*)alloc((size_t)LL * DD * DKK * 2);
  __hip_bfloat16* encb  = (__hip_bfloat16*)alloc((size_t)32 * SS * DD * 2);
  int KS = 64;
  while (KS > 8 && off + (size_t)KS * 32 * 8192 * 4 > ws_size) KS >>= 1;
  float* fpart = (float*)alloc((size_t)KS * 32 * 8192 * 4);
  const int kchunk = 32768 / KS;

  // ---- weight preprocessing (every call; deterministic)
  convT<<<dim3(FF / 32, DD / 32, LL), 256, 0, stream>>>(f_w1, w1T, DD, FF, DD * FF, 0);
  convT<<<dim3(DD / 32, FF / 32, LL), 256, 0, stream>>>(f_w2, w2T, FF, DD, DD * FF, 0);
  convT<<<dim3(2, 16, LL), 256, 0, stream>>>(sa_wq, qkvTs, DD, DKK, 192 * DD, 0);
  convT<<<dim3(2, 16, LL), 256, 0, stream>>>(sa_wk, qkvTs, DD, DKK, 192 * DD, 64);
  convT<<<dim3(2, 16, LL), 256, 0, stream>>>(sa_wv, qkvTs, DD, DKK, 192 * DD, 128);
  convT<<<dim3(2, 16, LL), 256, 0, stream>>>(ca_wq, qkvTc, DD, DKK, 192 * DD, 0);
  convT<<<dim3(2, 16, LL), 256, 0, stream>>>(ca_wk, qkvTc, DD, DKK, 192 * DD, 64);
  convT<<<dim3(2, 16, LL), 256, 0, stream>>>(ca_wv, qkvTc, DD, DKK, 192 * DD, 128);
  convT<<<dim3(16, 2, LL), 256, 0, stream>>>(sa_wo, woTs, DKK, DD, DD * DKK, 0);
  convT<<<dim3(16, 2, LL), 256, 0, stream>>>(ca_wo, woTc, DKK, DD, DD * DKK, 0);
  tobf16<<<4096, 256, 0, stream>>>(enc, encb);

  embed_kernel<<<4096, 256, 0, stream>>>(seq, emb, pes, x0, xb0);

  float* xc = x0; float* xa = x1;
  __hip_bfloat16* xbc = xb0; __hip_bfloat16* xba = xb1;

  for (int i = 0; i < LL; ++i) {
    const float* g0  = bn_g + (size_t)(i * 3 + 0) * DD;
    const float* be0 = bn_b + (size_t)(i * 3 + 0) * DD;
    const float* g1  = bn_g + (size_t)(i * 3 + 1) * DD;
    const float* be1 = bn_b + (size_t)(i * 3 + 1) * DD;
    const float* g2  = bn_g + (size_t)(i * 3 + 2) * DD;
    const float* be2 = bn_b + (size_t)(i * 3 + 2) * DD;

    // self-attn: reads xc/xbc -> writes xa/xba
    fused_attn<true><<<dim3(4, 32), 256, 0, stream>>>(
        xbc, xbc, qkvTs + (size_t)i * 192 * DD,
        sa_bq + i * DKK, sa_bk + i * DKK, sa_bv + i * DKK,
        woTs + (size_t)i * DD * DKK, sa_bo + (size_t)i * DD,
        xc, g0, be0, xa, xba);
    // cross-attn: reads xa/xba (q), encb (kv) -> writes xc/xbc
    fused_attn<false><<<dim3(4, 32), 256, 0, stream>>>(
        xba, encb, qkvTc + (size_t)i * 192 * DD,
        ca_bq + i * DKK, ca_bk + i * DKK, ca_bv + i * DKK,
        woTc + (size_t)i * DD * DKK, ca_bo + (size_t)i * DD,
        xa, g1, be1, xc, xbc);
    // FFN: w1 reads xbc; w2 residual xc -> writes xa/xba
    mm_bf16<1><<<dim3(16, 16), 256, 0, stream>>>(
        xbc, w1T + (size_t)i * DD * FF, DD, FF, f_b1 + (size_t)i * FF,
        h, nullptr, nullptr, nullptr, nullptr);
    mm_bf16<2><<<dim3(16, 4), 256, 0, stream>>>(
        h, w2T + (size_t)i * DD * FF, FF, DD, f_b2 + (size_t)i * DD,
        xba, xa, xc, g2, be2);

    { float* t = xc; xc = xa; xa = t; }
    { __hip_bfloat16* t = xbc; xbc = xba; xba = t; }
  }

  fgemm_part<<<dim3(8, KS), 256, 0, stream>>>(xc, out_w, fpart, kchunk);
  freduce<<<1000, 256, 0, stream>>>(fpart, out_b, out, KS);
}

// Round 4
// 672.530 us; speedup vs baseline: 3.4588x; 1.0825x over previous
//
#include <hip/hip_runtime.h>
#include <hip/hip_bf16.h>
#include <cstddef>

#define DD 512
#define DKK 64
#define SS 64
#define BS 2048
#define FF 2048
#define VV 8000
#define LL 4
#define BN_SCALE 0.9995003746f

typedef __attribute__((ext_vector_type(8))) short short8;
typedef __attribute__((ext_vector_type(4))) float f32x4;

// async global -> LDS, 16 bytes per lane. LDS dest: wave-uniform base + lane*16.
__device__ __forceinline__ void gload16(const void* g, void* l) {
  __builtin_amdgcn_global_load_lds((const __attribute__((address_space(1))) void*)g,
                                   (__attribute__((address_space(3))) void*)l, 16, 0, 0);
}

// ---------------------------------------------------------------- embedding (fp32 + bf16 mirror)
__global__ __launch_bounds__(256) void embed_kernel(
    const int* __restrict__ seq, const float* __restrict__ emb,
    const float* __restrict__ pes, float* __restrict__ x,
    __hip_bfloat16* __restrict__ xb) {
  int idx = blockIdx.x * 256 + threadIdx.x;     // BS*DD total
  int bs  = idx / DD;
  int d   = idx % DD;
  int s   = bs % SS;
  int tok = seq[bs];
  float v = emb[tok * DD + d] + pes[s * DD + d];
  x[idx]  = v;
  xb[idx] = __float2bfloat16(v);
}

// ---------------------------------------------------------------- fp32 -> bf16 elementwise
__global__ __launch_bounds__(256) void tobf16(
    const float* __restrict__ in, __hip_bfloat16* __restrict__ o) {
  int i = blockIdx.x * 256 + threadIdx.x;
  o[i] = __float2bfloat16(in[i]);
}

// ---------------------------------------------------------------- generic weight transpose+convert
__global__ __launch_bounds__(256) void convT(
    const float* __restrict__ w, __hip_bfloat16* __restrict__ o,
    int K, int N, int oLS, int oRowOff) {
  __shared__ float t[32][33];
  const float* wl = w + (size_t)blockIdx.z * K * N;
  __hip_bfloat16* ol = o + (size_t)blockIdx.z * oLS + (size_t)oRowOff * K;
  int n0 = blockIdx.x * 32, k0 = blockIdx.y * 32;
  int tx = threadIdx.x & 31, ty = threadIdx.x >> 5;
#pragma unroll
  for (int p = 0; p < 4; ++p)
    t[ty + p * 8][tx] = wl[(size_t)(k0 + ty + p * 8) * N + n0 + tx];
  __syncthreads();
#pragma unroll
  for (int p = 0; p < 4; ++p)
    ol[(size_t)(n0 + ty + p * 8) * K + k0 + tx] = __float2bfloat16(t[tx][ty + p * 8]);
}

// batched qkv transpose: z = side*L*3 + layer*3 + which ; src [512][64] -> dst rows which*64..+63 of [192][512]
__global__ __launch_bounds__(256) void convQKV(
    const float* __restrict__ p0, const float* __restrict__ p1, const float* __restrict__ p2,
    const float* __restrict__ p3, const float* __restrict__ p4, const float* __restrict__ p5,
    __hip_bfloat16* __restrict__ dst_s, __hip_bfloat16* __restrict__ dst_c) {
  __shared__ float t[32][33];
  int z = blockIdx.z;
  int side = z / (LL * 3), rem = z % (LL * 3), i = rem / 3, which = rem % 3;
  int sel = side * 3 + which;
  const float* base = sel == 0 ? p0 : sel == 1 ? p1 : sel == 2 ? p2 : sel == 3 ? p3 : sel == 4 ? p4 : p5;
  const float* wl = base + (size_t)i * DD * DKK;
  __hip_bfloat16* ol = (side ? dst_c : dst_s) + (size_t)i * 192 * DD + (size_t)which * 64 * DD;
  int n0 = blockIdx.x * 32, k0 = blockIdx.y * 32;
  int tx = threadIdx.x & 31, ty = threadIdx.x >> 5;
#pragma unroll
  for (int p = 0; p < 4; ++p)
    t[ty + p * 8][tx] = wl[(size_t)(k0 + ty + p * 8) * DKK + n0 + tx];
  __syncthreads();
#pragma unroll
  for (int p = 0; p < 4; ++p)
    ol[(size_t)(n0 + ty + p * 8) * DD + k0 + tx] = __float2bfloat16(t[tx][ty + p * 8]);
}

// batched wo transpose: z = side*L + layer ; src [64][512] -> dst [512][64]
__global__ __launch_bounds__(256) void convWO(
    const float* __restrict__ ps, const float* __restrict__ pc,
    __hip_bfloat16* __restrict__ dst_s, __hip_bfloat16* __restrict__ dst_c) {
  __shared__ float t[32][33];
  int z = blockIdx.z;
  int side = z / LL, i = z % LL;
  const float* wl = (side ? pc : ps) + (size_t)i * DKK * DD;
  __hip_bfloat16* ol = (side ? dst_c : dst_s) + (size_t)i * DD * DKK;
  int n0 = blockIdx.x * 32, k0 = blockIdx.y * 32;
  int tx = threadIdx.x & 31, ty = threadIdx.x >> 5;
#pragma unroll
  for (int p = 0; p < 4; ++p)
    t[ty + p * 8][tx] = wl[(size_t)(k0 + ty + p * 8) * DD + n0 + tx];
  __syncthreads();
#pragma unroll
  for (int p = 0; p < 4; ++p)
    ol[(size_t)(n0 + ty + p * 8) * DKK + k0 + tx] = __float2bfloat16(t[tx][ty + p * 8]);
}

// ---------------------------------------------------------------- fused attention block
template <bool CAUSAL>
__global__ __launch_bounds__(256) void fused_attn(
    const __hip_bfloat16* __restrict__ qin,
    const __hip_bfloat16* __restrict__ kvin,
    const __hip_bfloat16* __restrict__ qkvT,
    const float* __restrict__ bq, const float* __restrict__ bk, const float* __restrict__ bv,
    const __hip_bfloat16* __restrict__ woT,
    const float* __restrict__ bo,
    const float* __restrict__ xres,
    const float* __restrict__ gamma, const float* __restrict__ beta,
    float* __restrict__ xout, __hip_bfloat16* __restrict__ xbout) {
  __shared__ __hip_bfloat16 Ws[192][72];
  __shared__ __hip_bfloat16 Qb[64][72], Kb[64][72], Vt[64][72], Pb[64][72], Hb[64][72];
  const int tid  = threadIdx.x;
  const int w    = tid >> 6;
  const int lane = tid & 63;
  const int l15  = lane & 15, lhi = lane >> 4;
  const int b    = blockIdx.y;
  const int col0 = blockIdx.x * 128;
  const size_t abase = (size_t)(b * SS) * DD;

  // ---- phase A: Q,K,V = [X | Xkv] @ Wqkv
  f32x4 acc[12] = {};
  for (int kc = 0; kc < DD; kc += 64) {
    __syncthreads();
#pragma unroll
    for (int u = 0; u < 6; ++u) {
      int idx = u * 256 + tid; int row = idx >> 3; int c8 = idx & 7;
      *(short8*)&Ws[row][c8 * 8] = *(const short8*)(qkvT + (size_t)row * DD + kc + c8 * 8);
    }
    __syncthreads();
#pragma unroll
    for (int kk = 0; kk < 2; ++kk) {
      short8 aq  = *(const short8*)(qin  + abase + (size_t)(w * 16 + l15) * DD + kc + kk * 32 + lhi * 8);
      short8 akv = *(const short8*)(kvin + abase + (size_t)(w * 16 + l15) * DD + kc + kk * 32 + lhi * 8);
#pragma unroll
      for (int f = 0; f < 12; ++f) {
        short8 bfr = *(const short8*)&Ws[f * 16 + l15][kk * 32 + lhi * 8];
        acc[f] = __builtin_amdgcn_mfma_f32_16x16x32_bf16(f < 4 ? aq : akv, bfr, acc[f], 0, 0, 0);
      }
    }
  }
#pragma unroll
  for (int f = 0; f < 12; ++f) {
    int c = (f & 3) * 16 + l15;
#pragma unroll
    for (int r = 0; r < 4; ++r) {
      int row = w * 16 + lhi * 4 + r;
      if (f < 4)      Qb[row][c] = __float2bfloat16((acc[f][r] + bq[c]) * 0.125f);
      else if (f < 8) Kb[row][c] = __float2bfloat16(acc[f][r] + bk[c]);
      else            Vt[c][row] = __float2bfloat16(acc[f][r] + bv[c]);
    }
  }
  __syncthreads();

  // ---- phase B: S = Q @ K^T
  f32x4 sacc[4] = {};
#pragma unroll
  for (int kk = 0; kk < 2; ++kk) {
    short8 aq = *(const short8*)&Qb[w * 16 + l15][kk * 32 + lhi * 8];
#pragma unroll
    for (int f = 0; f < 4; ++f) {
      short8 bfr = *(const short8*)&Kb[f * 16 + l15][kk * 32 + lhi * 8];
      sacc[f] = __builtin_amdgcn_mfma_f32_16x16x32_bf16(aq, bfr, sacc[f], 0, 0, 0);
    }
  }
#pragma unroll
  for (int r = 0; r < 4; ++r) {
    int qr = w * 16 + lhi * 4 + r;
    float sv[4];
    float m = -3.0e38f;
#pragma unroll
    for (int f = 0; f < 4; ++f) {
      int kt = f * 16 + l15;
      bool valid = (!CAUSAL) || (kt < qr);
      sv[f] = valid ? sacc[f][r] : -3.0e38f;
      m = fmaxf(m, sv[f]);
    }
#pragma unroll
    for (int off = 1; off < 16; off <<= 1) m = fmaxf(m, __shfl_xor(m, off));
    float pv[4], sum = 0.f;
#pragma unroll
    for (int f = 0; f < 4; ++f) {
      pv[f] = (sv[f] > -1.0e38f) ? __expf(sv[f] - m) : 0.f;
      sum += pv[f];
    }
#pragma unroll
    for (int off = 1; off < 16; off <<= 1) sum += __shfl_xor(sum, off);
    float rs = sum > 0.f ? 1.f / sum : 0.f;
#pragma unroll
    for (int f = 0; f < 4; ++f)
      Pb[qr][f * 16 + l15] = __float2bfloat16(pv[f] * rs);
  }
  __syncthreads();

  // ---- phase C: head = P @ V
  f32x4 hacc[4] = {};
#pragma unroll
  for (int kk = 0; kk < 2; ++kk) {
    short8 ap = *(const short8*)&Pb[w * 16 + l15][kk * 32 + lhi * 8];
#pragma unroll
    for (int f = 0; f < 4; ++f) {
      short8 bfr = *(const short8*)&Vt[f * 16 + l15][kk * 32 + lhi * 8];
      hacc[f] = __builtin_amdgcn_mfma_f32_16x16x32_bf16(ap, bfr, hacc[f], 0, 0, 0);
    }
  }
#pragma unroll
  for (int f = 0; f < 4; ++f)
#pragma unroll
    for (int r = 0; r < 4; ++r)
      Hb[w * 16 + lhi * 4 + r][f * 16 + l15] = __float2bfloat16(hacc[f][r]);
  __syncthreads();

  // ---- phase D: out = head @ Wo + bo, +residual, BN
  f32x4 oacc[8] = {};
#pragma unroll
  for (int kk = 0; kk < 2; ++kk) {
    short8 ah = *(const short8*)&Hb[w * 16 + l15][kk * 32 + lhi * 8];
#pragma unroll
    for (int f = 0; f < 8; ++f) {
      short8 bfr = *(const short8*)(woT + (size_t)(col0 + f * 16 + l15) * DKK + kk * 32 + lhi * 8);
      oacc[f] = __builtin_amdgcn_mfma_f32_16x16x32_bf16(ah, bfr, oacc[f], 0, 0, 0);
    }
  }
#pragma unroll
  for (int f = 0; f < 8; ++f) {
    int c = col0 + f * 16 + l15;
    float g = gamma[c], be = beta[c], bb = bo[c];
#pragma unroll
    for (int r = 0; r < 4; ++r) {
      int row = b * SS + w * 16 + lhi * 4 + r;
      float v = oacc[f][r] + bb;
      float res = xres[(size_t)row * DD + c] + v;
      float y = g * (res * BN_SCALE) + be;
      xout[(size_t)row * DD + c]  = y;
      xbout[(size_t)row * DD + c] = __float2bfloat16(y);
    }
  }
}

// ---------------------------------------------------------------- bf16 MFMA GEMM (m97-style: gload_lds + dbuf 2-phase)
// A [M,K] bf16 rm; BT [N,K] bf16 rm. EPI 1: bias+relu->bf16 ; EPI 2: bias+res+BN->fp32+bf16
template <int BM, int BN, int WM, int WN, int EPI>
__global__ __launch_bounds__(256) void mm_bf16(
    const __hip_bfloat16* __restrict__ A, const __hip_bfloat16* __restrict__ BT,
    int K, int N, const float* __restrict__ bias,
    __hip_bfloat16* __restrict__ outb, float* __restrict__ outf,
    const float* __restrict__ xres,
    const float* __restrict__ gamma, const float* __restrict__ beta) {
  constexpr int NA = BM * 64 / 8 / 256;          // A gloads/thread
  constexpr int NB = BN * 64 / 8 / 256;
  constexpr int FM = BM / (WM * 16), FN = BN / (WN * 16);
  __shared__ __align__(16) __hip_bfloat16 As[2][BM * 64];
  __shared__ __align__(16) __hip_bfloat16 Bs[2][BN * 64];
  const int tid = threadIdx.x, lane = tid & 63, w = tid >> 6;
  const int wr = w / WN, wc = w % WN;
  const int l15 = lane & 15, lhi = lane >> 4;
  const int row0 = blockIdx.x * BM, col0 = blockIdx.y * BN;
  f32x4 acc[FM][FN] = {};

  auto stage = [&](int buf, int kc) {
#pragma unroll
    for (int c = 0; c < NA; ++c) {
      int j = c * 256 + tid;
      int r = j >> 3, c8 = j & 7;
      gload16(A + (size_t)(row0 + r) * K + kc + c8 * 8,
              &As[buf][(c * 256 + w * 64) * 8]);
    }
#pragma unroll
    for (int c = 0; c < NB; ++c) {
      int j = c * 256 + tid;
      int r = j >> 3, c8 = j & 7;
      gload16(BT + (size_t)(col0 + r) * K + kc + c8 * 8,
              &Bs[buf][(c * 256 + w * 64) * 8]);
    }
  };

  stage(0, 0);
  __syncthreads();                               // drains vmcnt before barrier
  const int NK = K / 64;
  for (int t = 0; t < NK; ++t) {
    int buf = t & 1;
    if (t + 1 < NK) stage(buf ^ 1, (t + 1) * 64);
#pragma unroll
    for (int kk = 0; kk < 2; ++kk) {
      short8 af[FM], bfm[FN];
#pragma unroll
      for (int f = 0; f < FM; ++f)
        af[f] = *(const short8*)(&As[buf][(wr * FM * 16 + f * 16 + l15) * 64 + kk * 32 + lhi * 8]);
#pragma unroll
      for (int f = 0; f < FN; ++f)
        bfm[f] = *(const short8*)(&Bs[buf][(wc * FN * 16 + f * 16 + l15) * 64 + kk * 32 + lhi * 8]);
#pragma unroll
      for (int fm = 0; fm < FM; ++fm)
#pragma unroll
        for (int fn = 0; fn < FN; ++fn)
          acc[fm][fn] = __builtin_amdgcn_mfma_f32_16x16x32_bf16(af[fm], bfm[fn], acc[fm][fn], 0, 0, 0);
    }
    __syncthreads();                             // drains vmcnt (next tile) + protects buf reuse
  }

#pragma unroll
  for (int fm = 0; fm < FM; ++fm)
#pragma unroll
    for (int r = 0; r < 4; ++r) {
      int row = row0 + wr * FM * 16 + fm * 16 + lhi * 4 + r;
#pragma unroll
      for (int fn = 0; fn < FN; ++fn) {
        int col = col0 + wc * FN * 16 + fn * 16 + l15;
        float v = acc[fm][fn][r] + bias[col];
        if (EPI == 1) {
          v = v > 0.f ? v : 0.f;
          outb[(size_t)row * N + col] = __float2bfloat16(v);
        } else {
          float sres = xres[(size_t)row * N + col] + v;
          float y = gamma[col] * (sres * BN_SCALE) + beta[col];
          outf[(size_t)row * N + col] = y;
          outb[(size_t)row * N + col] = __float2bfloat16(y);
        }
      }
    }
}

// ---------------------------------------------------------------- final GEMM: split-K partials (atomic-free)
__global__ __launch_bounds__(256) void fgemm_part(
    const float* __restrict__ flat, const float* __restrict__ wout,
    float* __restrict__ fpart, int kchunk) {
  int c4 = blockIdx.x * 256 + threadIdx.x;
  const bool act = c4 < 2000;
  const int c4c = act ? c4 : 1999;
  const int k0 = blockIdx.y * kchunk;
  const float* Wp = wout + (size_t)k0 * VV + (size_t)c4c * 4;
  f32x4 acc[32] = {};
  for (int k = 0; k < kchunk; k += 4) {
    f32x4 w0 = *(const f32x4*)(Wp + (size_t)(k + 0) * VV);
    f32x4 w1 = *(const f32x4*)(Wp + (size_t)(k + 1) * VV);
    f32x4 w2 = *(const f32x4*)(Wp + (size_t)(k + 2) * VV);
    f32x4 w3 = *(const f32x4*)(Wp + (size_t)(k + 3) * VV);
#pragma unroll
    for (int bh = 0; bh < 2; ++bh) {
      f32x4 f[16];
#pragma unroll
      for (int b = 0; b < 16; ++b)
        f[b] = *(const f32x4*)(flat + (size_t)(bh * 16 + b) * (SS * DD) + k0 + k);
#pragma unroll
      for (int b = 0; b < 16; ++b) {
        int bb = bh * 16 + b;
        acc[bb] = acc[bb] + f[b].x * w0 + f[b].y * w1 + f[b].z * w2 + f[b].w * w3;
      }
    }
  }
  if (act) {
    float* pp = fpart + (size_t)blockIdx.y * 32 * 8192 + (size_t)c4 * 4;
#pragma unroll
    for (int b = 0; b < 32; ++b)
      *(f32x4*)(pp + (size_t)b * 8192) = acc[b];
  }
}

__global__ __launch_bounds__(256) void freduce(
    const float* __restrict__ fpart, const float* __restrict__ out_b,
    float* __restrict__ out, int KS) {
  int i = blockIdx.x * 256 + threadIdx.x;
  int b = i / VV, c = i % VV;
  float s = out_b[c];
  for (int ks = 0; ks < KS; ++ks)
    s += fpart[((size_t)ks * 32 + b) * 8192 + c];
  out[i] = s;
}

// ---------------------------------------------------------------- launch
extern "C" void kernel_launch(void* const* d_in, const int* in_sizes, int n_in,
                              void* d_out, int out_size, void* d_ws, size_t ws_size,
                              hipStream_t stream) {
  const int*   seq   = (const int*)  d_in[0];
  const float* enc   = (const float*)d_in[1];
  const float* pes   = (const float*)d_in[2];
  const float* emb   = (const float*)d_in[3];
  const float* sa_wq = (const float*)d_in[4];
  const float* sa_bq = (const float*)d_in[5];
  const float* sa_wk = (const float*)d_in[6];
  const float* sa_bk = (const float*)d_in[7];
  const float* sa_wv = (const float*)d_in[8];
  const float* sa_bv = (const float*)d_in[9];
  const float* sa_wo = (const float*)d_in[10];
  const float* sa_bo = (const float*)d_in[11];
  const float* ca_wq = (const float*)d_in[12];
  const float* ca_bq = (const float*)d_in[13];
  const float* ca_wk = (const float*)d_in[14];
  const float* ca_bk = (const float*)d_in[15];
  const float* ca_wv = (const float*)d_in[16];
  const float* ca_bv = (const float*)d_in[17];
  const float* ca_wo = (const float*)d_in[18];
  const float* ca_bo = (const float*)d_in[19];
  const float* f_w1  = (const float*)d_in[20];
  const float* f_b1  = (const float*)d_in[21];
  const float* f_w2  = (const float*)d_in[22];
  const float* f_b2  = (const float*)d_in[23];
  const float* bn_g  = (const float*)d_in[24];
  const float* bn_b  = (const float*)d_in[25];
  const float* out_w = (const float*)d_in[26];
  const float* out_b = (const float*)d_in[27];
  float* out = (float*)d_out;

  // ---- ws carve-up
  char* wp = (char*)d_ws;
  size_t off = 0;
  auto alloc = [&](size_t bytes) { void* p = wp + off; off += (bytes + 255) & ~(size_t)255; return p; };
  float* x0 = (float*)alloc((size_t)BS * DD * 4);
  float* x1 = (float*)alloc((size_t)BS * DD * 4);
  __hip_bfloat16* xb0 = (__hip_bfloat16*)alloc((size_t)BS * DD * 2);
  __hip_bfloat16* xb1 = (__hip_bfloat16*)alloc((size_t)BS * DD * 2);
  __hip_bfloat16* h   = (__hip_bfloat16*)alloc((size_t)BS * FF * 2);
  __hip_bfloat16* w1T = (__hip_bfloat16*)alloc((size_t)LL * DD * FF * 2);
  __hip_bfloat16* w2T = (__hip_bfloat16*)alloc((size_t)LL * DD * FF * 2);
  __hip_bfloat16* qkvTs = (__hip_bfloat16*)alloc((size_t)LL * 192 * DD * 2);
  __hip_bfloat16* qkvTc = (__hip_bfloat16*)alloc((size_t)LL * 192 * DD * 2);
  __hip_bfloat16* woTs  = (__hip_bfloat16*)alloc((size_t)LL * DD * DKK * 2);
  __hip_bfloat16* woTc  = (__hip_bfloat16*)alloc((size_t)LL * DD * DKK * 2);
  __hip_bfloat16* encb  = (__hip_bfloat16*)alloc((size_t)32 * SS * DD * 2);
  int KS = 64;
  while (KS > 8 && off + (size_t)KS * 32 * 8192 * 4 > ws_size) KS >>= 1;
  float* fpart = (float*)alloc((size_t)KS * 32 * 8192 * 4);
  const int kchunk = 32768 / KS;

  // ---- weight preprocessing (batched; every call, deterministic)
  convT<<<dim3(FF / 32, DD / 32, LL), 256, 0, stream>>>(f_w1, w1T, DD, FF, DD * FF, 0);
  convT<<<dim3(DD / 32, FF / 32, LL), 256, 0, stream>>>(f_w2, w2T, FF, DD, DD * FF, 0);
  convQKV<<<dim3(2, 16, 2 * LL * 3), 256, 0, stream>>>(
      sa_wq, sa_wk, sa_wv, ca_wq, ca_wk, ca_wv, qkvTs, qkvTc);
  convWO<<<dim3(16, 2, 2 * LL), 256, 0, stream>>>(sa_wo, ca_wo, woTs, woTc);
  tobf16<<<4096, 256, 0, stream>>>(enc, encb);
  embed_kernel<<<4096, 256, 0, stream>>>(seq, emb, pes, x0, xb0);

  float* xc = x0; float* xa = x1;
  __hip_bfloat16* xbc = xb0; __hip_bfloat16* xba = xb1;

  for (int i = 0; i < LL; ++i) {
    const float* g0  = bn_g + (size_t)(i * 3 + 0) * DD;
    const float* be0 = bn_b + (size_t)(i * 3 + 0) * DD;
    const float* g1  = bn_g + (size_t)(i * 3 + 1) * DD;
    const float* be1 = bn_b + (size_t)(i * 3 + 1) * DD;
    const float* g2  = bn_g + (size_t)(i * 3 + 2) * DD;
    const float* be2 = bn_b + (size_t)(i * 3 + 2) * DD;

    // self-attn: reads xc/xbc -> writes xa/xba
    fused_attn<true><<<dim3(4, 32), 256, 0, stream>>>(
        xbc, xbc, qkvTs + (size_t)i * 192 * DD,
        sa_bq + i * DKK, sa_bk + i * DKK, sa_bv + i * DKK,
        woTs + (size_t)i * DD * DKK, sa_bo + (size_t)i * DD,
        xc, g0, be0, xa, xba);
    // cross-attn: reads xa/xba (q), encb (kv) -> writes xc/xbc
    fused_attn<false><<<dim3(4, 32), 256, 0, stream>>>(
        xba, encb, qkvTc + (size_t)i * 192 * DD,
        ca_bq + i * DKK, ca_bk + i * DKK, ca_bv + i * DKK,
        woTc + (size_t)i * DD * DKK, ca_bo + (size_t)i * DD,
        xa, g1, be1, xc, xbc);
    // FFN
    mm_bf16<128, 128, 2, 2, 1><<<dim3(16, 16), 256, 0, stream>>>(
        xbc, w1T + (size_t)i * DD * FF, DD, FF, f_b1 + (size_t)i * FF,
        h, nullptr, nullptr, nullptr, nullptr);
    mm_bf16<64, 128, 1, 4, 2><<<dim3(32, 4), 256, 0, stream>>>(
        h, w2T + (size_t)i * DD * FF, FF, DD, f_b2 + (size_t)i * DD,
        xba, xa, xc, g2, be2);

    { float* t = xc; xc = xa; xa = t; }
    { __hip_bfloat16* t = xbc; xbc = xba; xba = t; }
  }

  fgemm_part<<<dim3(8, KS), 256, 0, stream>>>(xc, out_w, fpart, kchunk);
  freduce<<<1000, 256, 0, stream>>>(fpart, out_b, out, KS);
}

// Round 5
// 550.504 us; speedup vs baseline: 4.2255x; 1.2217x over previous
//
#include <hip/hip_runtime.h>
#include <hip/hip_bf16.h>
#include <cstddef>

#define DD 512
#define DKK 64
#define SS 64
#define BS 2048
#define FF 2048
#define VV 8000
#define LL 4
#define BN_SCALE 0.9995003746f
#define FG_KS 64
#define FG_KCH 512

typedef __attribute__((ext_vector_type(8))) short short8;
typedef __attribute__((ext_vector_type(4))) float f32x4;

// async global -> LDS, 16 bytes per lane. LDS dest: wave-uniform base + lane*16.
__device__ __forceinline__ void gload16(const void* g, void* l) {
  __builtin_amdgcn_global_load_lds((const __attribute__((address_space(1))) void*)g,
                                   (__attribute__((address_space(3))) void*)l, 16, 0, 0);
}

// ---------------------------------------------------------------- merged preprocessing
// sections: [0,4096) w1T ; [4096,8192) w2T ; [8192,8960) qkvT ; [8960,9216) woT ;
//           [9216,13312) enc->bf16 ; [13312,17408) embed
__global__ __launch_bounds__(256) void prep_kernel(
    const float* __restrict__ f_w1, const float* __restrict__ f_w2,
    const float* __restrict__ sa_wq, const float* __restrict__ sa_wk, const float* __restrict__ sa_wv,
    const float* __restrict__ ca_wq, const float* __restrict__ ca_wk, const float* __restrict__ ca_wv,
    const float* __restrict__ sa_wo, const float* __restrict__ ca_wo,
    const float* __restrict__ enc, const int* __restrict__ seq,
    const float* __restrict__ emb, const float* __restrict__ pes,
    __hip_bfloat16* __restrict__ w1T, __hip_bfloat16* __restrict__ w2T,
    __hip_bfloat16* __restrict__ qkvTs, __hip_bfloat16* __restrict__ qkvTc,
    __hip_bfloat16* __restrict__ woTs, __hip_bfloat16* __restrict__ woTc,
    __hip_bfloat16* __restrict__ encb, float* __restrict__ x, __hip_bfloat16* __restrict__ xb) {
  __shared__ float t[32][33];
  const int bid = blockIdx.x;
  const int tid = threadIdx.x;
  const int tx = tid & 31, ty = tid >> 5;

  auto tr = [&](const float* src, int srcld, __hip_bfloat16* dst, int dstld, int n0, int k0) {
#pragma unroll
    for (int p = 0; p < 4; ++p)
      t[ty + p * 8][tx] = src[(size_t)(k0 + ty + p * 8) * srcld + n0 + tx];
    __syncthreads();
#pragma unroll
    for (int p = 0; p < 4; ++p)
      dst[(size_t)(n0 + ty + p * 8) * dstld + k0 + tx] = __float2bfloat16(t[tx][ty + p * 8]);
  };

  if (bid < 4096) {                       // w1: [L][512][2048] -> [L][2048][512]
    int z = bid >> 10, rem = bid & 1023, kb = rem >> 6, nb = rem & 63;
    tr(f_w1 + (size_t)z * DD * FF, FF, w1T + (size_t)z * FF * DD, DD, nb * 32, kb * 32);
  } else if (bid < 8192) {                // w2: [L][2048][512] -> [L][512][2048]
    int q = bid - 4096;
    int z = q >> 10, rem = q & 1023, nb = rem & 15, kb = rem >> 4;
    tr(f_w2 + (size_t)z * FF * DD, DD, w2T + (size_t)z * DD * FF, FF, nb * 32, kb * 32);
  } else if (bid < 8960) {                // qkv: [512][64] -> rows of [192][512]
    int q = bid - 8192;
    int z = q >> 5, rem = q & 31, nb = rem & 1, kb = rem >> 1;
    int side = z / 12, r2 = z % 12, i = r2 / 3, which = r2 % 3;
    int sel = side * 3 + which;
    const float* base = sel == 0 ? sa_wq : sel == 1 ? sa_wk : sel == 2 ? sa_wv
                      : sel == 3 ? ca_wq : sel == 4 ? ca_wk : ca_wv;
    __hip_bfloat16* dst = (side ? qkvTc : qkvTs) + (size_t)i * 192 * DD + (size_t)which * 64 * DD;
    tr(base + (size_t)i * DD * DKK, DKK, dst, DD, nb * 32, kb * 32);
  } else if (bid < 9216) {                // wo: [64][512] -> [512][64]
    int q = bid - 8960;
    int z = q >> 5, rem = q & 31, nb = rem >> 1, kb = rem & 1;
    int side = z / LL, i = z % LL;
    const float* base = (side ? ca_wo : sa_wo) + (size_t)i * DKK * DD;
    __hip_bfloat16* dst = (side ? woTc : woTs) + (size_t)i * DD * DKK;
    tr(base, DD, dst, DKK, nb * 32, kb * 32);
  } else if (bid < 13312) {               // enc -> bf16
    int i = (bid - 9216) * 256 + tid;
    encb[i] = __float2bfloat16(enc[i]);
  } else {                                // embedding
    int idx = (bid - 13312) * 256 + tid;
    int bs = idx / DD, d = idx % DD, s = bs % SS;
    float v = emb[(size_t)seq[bs] * DD + d] + pes[s * DD + d];
    x[idx]  = v;
    xb[idx] = __float2bfloat16(v);
  }
}

// ---------------------------------------------------------------- fused attention block
template <bool CAUSAL>
__global__ __launch_bounds__(256) void fused_attn(
    const __hip_bfloat16* __restrict__ qin,
    const __hip_bfloat16* __restrict__ kvin,
    const __hip_bfloat16* __restrict__ qkvT,
    const float* __restrict__ bq, const float* __restrict__ bk, const float* __restrict__ bv,
    const __hip_bfloat16* __restrict__ woT,
    const float* __restrict__ bo,
    const float* __restrict__ xres,
    const float* __restrict__ gamma, const float* __restrict__ beta,
    float* __restrict__ xout, __hip_bfloat16* __restrict__ xbout) {
  __shared__ __hip_bfloat16 Ws[192][72];
  __shared__ __hip_bfloat16 Qb[64][72], Kb[64][72], Vt[64][72], Pb[64][72], Hb[64][72];
  const int tid  = threadIdx.x;
  const int w    = tid >> 6;
  const int lane = tid & 63;
  const int l15  = lane & 15, lhi = lane >> 4;
  const int b    = blockIdx.y;
  const int col0 = blockIdx.x * 128;
  const size_t abase = (size_t)(b * SS) * DD;

  // ---- phase A: Q,K,V = [X | Xkv] @ Wqkv
  f32x4 acc[12] = {};
  for (int kc = 0; kc < DD; kc += 64) {
    __syncthreads();
#pragma unroll
    for (int u = 0; u < 6; ++u) {
      int idx = u * 256 + tid; int row = idx >> 3; int c8 = idx & 7;
      *(short8*)&Ws[row][c8 * 8] = *(const short8*)(qkvT + (size_t)row * DD + kc + c8 * 8);
    }
    __syncthreads();
#pragma unroll
    for (int kk = 0; kk < 2; ++kk) {
      short8 aq  = *(const short8*)(qin  + abase + (size_t)(w * 16 + l15) * DD + kc + kk * 32 + lhi * 8);
      short8 akv = *(const short8*)(kvin + abase + (size_t)(w * 16 + l15) * DD + kc + kk * 32 + lhi * 8);
#pragma unroll
      for (int f = 0; f < 12; ++f) {
        short8 bfr = *(const short8*)&Ws[f * 16 + l15][kk * 32 + lhi * 8];
        acc[f] = __builtin_amdgcn_mfma_f32_16x16x32_bf16(f < 4 ? aq : akv, bfr, acc[f], 0, 0, 0);
      }
    }
  }
#pragma unroll
  for (int f = 0; f < 12; ++f) {
    int c = (f & 3) * 16 + l15;
#pragma unroll
    for (int r = 0; r < 4; ++r) {
      int row = w * 16 + lhi * 4 + r;
      if (f < 4)      Qb[row][c] = __float2bfloat16((acc[f][r] + bq[c]) * 0.125f);
      else if (f < 8) Kb[row][c] = __float2bfloat16(acc[f][r] + bk[c]);
      else            Vt[c][row] = __float2bfloat16(acc[f][r] + bv[c]);
    }
  }
  __syncthreads();

  // ---- phase B: S = Q @ K^T
  f32x4 sacc[4] = {};
#pragma unroll
  for (int kk = 0; kk < 2; ++kk) {
    short8 aq = *(const short8*)&Qb[w * 16 + l15][kk * 32 + lhi * 8];
#pragma unroll
    for (int f = 0; f < 4; ++f) {
      short8 bfr = *(const short8*)&Kb[f * 16 + l15][kk * 32 + lhi * 8];
      sacc[f] = __builtin_amdgcn_mfma_f32_16x16x32_bf16(aq, bfr, sacc[f], 0, 0, 0);
    }
  }
#pragma unroll
  for (int r = 0; r < 4; ++r) {
    int qr = w * 16 + lhi * 4 + r;
    float sv[4];
    float m = -3.0e38f;
#pragma unroll
    for (int f = 0; f < 4; ++f) {
      int kt = f * 16 + l15;
      bool valid = (!CAUSAL) || (kt < qr);
      sv[f] = valid ? sacc[f][r] : -3.0e38f;
      m = fmaxf(m, sv[f]);
    }
#pragma unroll
    for (int off = 1; off < 16; off <<= 1) m = fmaxf(m, __shfl_xor(m, off));
    float pv[4], sum = 0.f;
#pragma unroll
    for (int f = 0; f < 4; ++f) {
      pv[f] = (sv[f] > -1.0e38f) ? __expf(sv[f] - m) : 0.f;
      sum += pv[f];
    }
#pragma unroll
    for (int off = 1; off < 16; off <<= 1) sum += __shfl_xor(sum, off);
    float rs = sum > 0.f ? 1.f / sum : 0.f;
#pragma unroll
    for (int f = 0; f < 4; ++f)
      Pb[qr][f * 16 + l15] = __float2bfloat16(pv[f] * rs);
  }
  __syncthreads();

  // ---- phase C: head = P @ V
  f32x4 hacc[4] = {};
#pragma unroll
  for (int kk = 0; kk < 2; ++kk) {
    short8 ap = *(const short8*)&Pb[w * 16 + l15][kk * 32 + lhi * 8];
#pragma unroll
    for (int f = 0; f < 4; ++f) {
      short8 bfr = *(const short8*)&Vt[f * 16 + l15][kk * 32 + lhi * 8];
      hacc[f] = __builtin_amdgcn_mfma_f32_16x16x32_bf16(ap, bfr, hacc[f], 0, 0, 0);
    }
  }
#pragma unroll
  for (int f = 0; f < 4; ++f)
#pragma unroll
    for (int r = 0; r < 4; ++r)
      Hb[w * 16 + lhi * 4 + r][f * 16 + l15] = __float2bfloat16(hacc[f][r]);
  __syncthreads();

  // ---- phase D: out = head @ Wo + bo, +residual, BN
  f32x4 oacc[8] = {};
#pragma unroll
  for (int kk = 0; kk < 2; ++kk) {
    short8 ah = *(const short8*)&Hb[w * 16 + l15][kk * 32 + lhi * 8];
#pragma unroll
    for (int f = 0; f < 8; ++f) {
      short8 bfr = *(const short8*)(woT + (size_t)(col0 + f * 16 + l15) * DKK + kk * 32 + lhi * 8);
      oacc[f] = __builtin_amdgcn_mfma_f32_16x16x32_bf16(ah, bfr, oacc[f], 0, 0, 0);
    }
  }
#pragma unroll
  for (int f = 0; f < 8; ++f) {
    int c = col0 + f * 16 + l15;
    float g = gamma[c], be = beta[c], bb = bo[c];
#pragma unroll
    for (int r = 0; r < 4; ++r) {
      int row = b * SS + w * 16 + lhi * 4 + r;
      float v = oacc[f][r] + bb;
      float res = xres[(size_t)row * DD + c] + v;
      float y = g * (res * BN_SCALE) + be;
      xout[(size_t)row * DD + c]  = y;
      xbout[(size_t)row * DD + c] = __float2bfloat16(y);
    }
  }
}

// ---------------------------------------------------------------- bf16 MFMA GEMM (gload_lds + dbuf)
template <int BM, int BN, int WM, int WN, int EPI>
__global__ __launch_bounds__(256) void mm_bf16(
    const __hip_bfloat16* __restrict__ A, const __hip_bfloat16* __restrict__ BT,
    int K, int N, const float* __restrict__ bias,
    __hip_bfloat16* __restrict__ outb, float* __restrict__ outf,
    const float* __restrict__ xres,
    const float* __restrict__ gamma, const float* __restrict__ beta) {
  constexpr int NA = BM * 64 / 8 / 256;
  constexpr int NB = BN * 64 / 8 / 256;
  constexpr int FM = BM / (WM * 16), FN = BN / (WN * 16);
  __shared__ __align__(16) __hip_bfloat16 As[2][BM * 64];
  __shared__ __align__(16) __hip_bfloat16 Bs[2][BN * 64];
  const int tid = threadIdx.x, lane = tid & 63, w = tid >> 6;
  const int wr = w / WN, wc = w % WN;
  const int l15 = lane & 15, lhi = lane >> 4;
  const int row0 = blockIdx.x * BM, col0 = blockIdx.y * BN;
  f32x4 acc[FM][FN] = {};

  auto stage = [&](int buf, int kc) {
#pragma unroll
    for (int c = 0; c < NA; ++c) {
      int j = c * 256 + tid;
      int r = j >> 3, c8 = j & 7;
      gload16(A + (size_t)(row0 + r) * K + kc + c8 * 8,
              &As[buf][(c * 256 + w * 64) * 8]);
    }
#pragma unroll
    for (int c = 0; c < NB; ++c) {
      int j = c * 256 + tid;
      int r = j >> 3, c8 = j & 7;
      gload16(BT + (size_t)(col0 + r) * K + kc + c8 * 8,
              &Bs[buf][(c * 256 + w * 64) * 8]);
    }
  };

  stage(0, 0);
  __syncthreads();
  const int NK = K / 64;
  for (int t = 0; t < NK; ++t) {
    int buf = t & 1;
    if (t + 1 < NK) stage(buf ^ 1, (t + 1) * 64);
#pragma unroll
    for (int kk = 0; kk < 2; ++kk) {
      short8 af[FM], bfm[FN];
#pragma unroll
      for (int f = 0; f < FM; ++f)
        af[f] = *(const short8*)(&As[buf][(wr * FM * 16 + f * 16 + l15) * 64 + kk * 32 + lhi * 8]);
#pragma unroll
      for (int f = 0; f < FN; ++f)
        bfm[f] = *(const short8*)(&Bs[buf][(wc * FN * 16 + f * 16 + l15) * 64 + kk * 32 + lhi * 8]);
#pragma unroll
      for (int fm = 0; fm < FM; ++fm)
#pragma unroll
        for (int fn = 0; fn < FN; ++fn)
          acc[fm][fn] = __builtin_amdgcn_mfma_f32_16x16x32_bf16(af[fm], bfm[fn], acc[fm][fn], 0, 0, 0);
    }
    __syncthreads();
  }

#pragma unroll
  for (int fm = 0; fm < FM; ++fm)
#pragma unroll
    for (int r = 0; r < 4; ++r) {
      int row = row0 + wr * FM * 16 + fm * 16 + lhi * 4 + r;
#pragma unroll
      for (int fn = 0; fn < FN; ++fn) {
        int col = col0 + wc * FN * 16 + fn * 16 + l15;
        float v = acc[fm][fn][r] + bias[col];
        if (EPI == 1) {
          v = v > 0.f ? v : 0.f;
          outb[(size_t)row * N + col] = __float2bfloat16(v);
        } else {
          float sres = xres[(size_t)row * N + col] + v;
          float y = gamma[col] * (sres * BN_SCALE) + beta[col];
          outf[(size_t)row * N + col] = y;
          outb[(size_t)row * N + col] = __float2bfloat16(y);
        }
      }
    }
}

// ---------------------------------------------------------------- final GEMM: MFMA, on-the-fly W->bf16
// grid (32 col-blocks of 256, FG_KS k-chunks); W streamed via gload_lds, flat bf16 from L2
__global__ __launch_bounds__(256) void fgemm_mfma(
    const __hip_bfloat16* __restrict__ flatb, const float* __restrict__ wout,
    float* __restrict__ fpart) {
  __shared__ float Ws[2][32][257];          // pad 257: k*257 mod 32 == k -> 2-way (free)
  const int tid = threadIdx.x, lane = tid & 63, w = tid >> 6;
  const int l15 = lane & 15, lhi = lane >> 4;
  const int c0 = (blockIdx.x < 31) ? blockIdx.x * 256 : (VV - 256);  // overlap dup-writes: benign
  const int k0 = blockIdx.y * FG_KCH;
  f32x4 acc[2][4] = {};

  auto stageW = [&](int buf, int it) {
    const float* src = wout + (size_t)(k0 + it * 32) * VV + c0;
#pragma unroll
    for (int i = 0; i < 8; ++i) {
      int row = i * 4 + w;                  // one full 256-col row per wave-inst
      gload16(src + (size_t)row * VV + lane * 4, &Ws[buf][row][0]);
    }
  };

  stageW(0, 0);
  __syncthreads();
  for (int it = 0; it < 16; ++it) {
    int buf = it & 1;
    if (it + 1 < 16) stageW(buf ^ 1, it + 1);
    short8 af[2];
#pragma unroll
    for (int mt = 0; mt < 2; ++mt)
      af[mt] = *(const short8*)(flatb + (size_t)(mt * 16 + l15) * (SS * DD) + k0 + it * 32 + lhi * 8);
#pragma unroll
    for (int ct = 0; ct < 4; ++ct) {
      int coll = w * 64 + ct * 16 + l15;
      short8 bfr;
#pragma unroll
      for (int j = 0; j < 8; ++j) {
        __hip_bfloat16 hb = __float2bfloat16(Ws[buf][lhi * 8 + j][coll]);
        bfr[j] = *reinterpret_cast<const short*>(&hb);
      }
#pragma unroll
      for (int mt = 0; mt < 2; ++mt)
        acc[mt][ct] = __builtin_amdgcn_mfma_f32_16x16x32_bf16(af[mt], bfr, acc[mt][ct], 0, 0, 0);
    }
    __syncthreads();
  }

  float* pp = fpart + (size_t)blockIdx.y * 32 * VV;
#pragma unroll
  for (int mt = 0; mt < 2; ++mt)
#pragma unroll
    for (int ct = 0; ct < 4; ++ct)
#pragma unroll
      for (int r = 0; r < 4; ++r)
        pp[(size_t)(mt * 16 + lhi * 4 + r) * VV + c0 + w * 64 + ct * 16 + l15] = acc[mt][ct][r];
}

__global__ __launch_bounds__(256) void freduce(
    const float* __restrict__ fpart, const float* __restrict__ out_b,
    float* __restrict__ out) {
  int i = blockIdx.x * 256 + threadIdx.x;   // 256000 total
  int b = i / VV, c = i % VV;
  float s = out_b[c];
  for (int ks = 0; ks < FG_KS; ++ks)
    s += fpart[((size_t)ks * 32 + b) * VV + c];
  out[i] = s;
}

// ---------------------------------------------------------------- launch
extern "C" void kernel_launch(void* const* d_in, const int* in_sizes, int n_in,
                              void* d_out, int out_size, void* d_ws, size_t ws_size,
                              hipStream_t stream) {
  const int*   seq   = (const int*)  d_in[0];
  const float* enc   = (const float*)d_in[1];
  const float* pes   = (const float*)d_in[2];
  const float* emb   = (const float*)d_in[3];
  const float* sa_wq = (const float*)d_in[4];
  const float* sa_bq = (const float*)d_in[5];
  const float* sa_wk = (const float*)d_in[6];
  const float* sa_bk = (const float*)d_in[7];
  const float* sa_wv = (const float*)d_in[8];
  const float* sa_bv = (const float*)d_in[9];
  const float* sa_wo = (const float*)d_in[10];
  const float* sa_bo = (const float*)d_in[11];
  const float* ca_wq = (const float*)d_in[12];
  const float* ca_bq = (const float*)d_in[13];
  const float* ca_wk = (const float*)d_in[14];
  const float* ca_bk = (const float*)d_in[15];
  const float* ca_wv = (const float*)d_in[16];
  const float* ca_bv = (const float*)d_in[17];
  const float* ca_wo = (const float*)d_in[18];
  const float* ca_bo = (const float*)d_in[19];
  const float* f_w1  = (const float*)d_in[20];
  const float* f_b1  = (const float*)d_in[21];
  const float* f_w2  = (const float*)d_in[22];
  const float* f_b2  = (const float*)d_in[23];
  const float* bn_g  = (const float*)d_in[24];
  const float* bn_b  = (const float*)d_in[25];
  const float* out_w = (const float*)d_in[26];
  const float* out_b = (const float*)d_in[27];
  float* out = (float*)d_out;

  // ---- ws carve-up
  char* wp = (char*)d_ws;
  size_t off = 0;
  auto alloc = [&](size_t bytes) { void* p = wp + off; off += (bytes + 255) & ~(size_t)255; return p; };
  float* x0 = (float*)alloc((size_t)BS * DD * 4);
  float* x1 = (float*)alloc((size_t)BS * DD * 4);
  __hip_bfloat16* xb0 = (__hip_bfloat16*)alloc((size_t)BS * DD * 2);
  __hip_bfloat16* xb1 = (__hip_bfloat16*)alloc((size_t)BS * DD * 2);
  __hip_bfloat16* h   = (__hip_bfloat16*)alloc((size_t)BS * FF * 2);
  __hip_bfloat16* w1T = (__hip_bfloat16*)alloc((size_t)LL * DD * FF * 2);
  __hip_bfloat16* w2T = (__hip_bfloat16*)alloc((size_t)LL * DD * FF * 2);
  __hip_bfloat16* qkvTs = (__hip_bfloat16*)alloc((size_t)LL * 192 * DD * 2);
  __hip_bfloat16* qkvTc = (__hip_bfloat16*)alloc((size_t)LL * 192 * DD * 2);
  __hip_bfloat16* woTs  = (__hip_bfloat16*)alloc((size_t)LL * DD * DKK * 2);
  __hip_bfloat16* woTc  = (__hip_bfloat16*)alloc((size_t)LL * DD * DKK * 2);
  __hip_bfloat16* encb  = (__hip_bfloat16*)alloc((size_t)32 * SS * DD * 2);
  float* fpart = (float*)alloc((size_t)FG_KS * 32 * VV * 4);

  // ---- single preprocessing launch
  prep_kernel<<<17408, 256, 0, stream>>>(
      f_w1, f_w2, sa_wq, sa_wk, sa_wv, ca_wq, ca_wk, ca_wv, sa_wo, ca_wo,
      enc, seq, emb, pes,
      w1T, w2T, qkvTs, qkvTc, woTs, woTc, encb, x0, xb0);

  float* xc = x0; float* xa = x1;
  __hip_bfloat16* xbc = xb0; __hip_bfloat16* xba = xb1;

  for (int i = 0; i < LL; ++i) {
    const float* g0  = bn_g + (size_t)(i * 3 + 0) * DD;
    const float* be0 = bn_b + (size_t)(i * 3 + 0) * DD;
    const float* g1  = bn_g + (size_t)(i * 3 + 1) * DD;
    const float* be1 = bn_b + (size_t)(i * 3 + 1) * DD;
    const float* g2  = bn_g + (size_t)(i * 3 + 2) * DD;
    const float* be2 = bn_b + (size_t)(i * 3 + 2) * DD;

    // self-attn: reads xc/xbc -> writes xa/xba
    fused_attn<true><<<dim3(4, 32), 256, 0, stream>>>(
        xbc, xbc, qkvTs + (size_t)i * 192 * DD,
        sa_bq + i * DKK, sa_bk + i * DKK, sa_bv + i * DKK,
        woTs + (size_t)i * DD * DKK, sa_bo + (size_t)i * DD,
        xc, g0, be0, xa, xba);
    // cross-attn: reads xa/xba (q), encb (kv) -> writes xc/xbc
    fused_attn<false><<<dim3(4, 32), 256, 0, stream>>>(
        xba, encb, qkvTc + (size_t)i * 192 * DD,
        ca_bq + i * DKK, ca_bk + i * DKK, ca_bv + i * DKK,
        woTc + (size_t)i * DD * DKK, ca_bo + (size_t)i * DD,
        xa, g1, be1, xc, xbc);
    // FFN
    mm_bf16<128, 128, 2, 2, 1><<<dim3(16, 16), 256, 0, stream>>>(
        xbc, w1T + (size_t)i * DD * FF, DD, FF, f_b1 + (size_t)i * FF,
        h, nullptr, nullptr, nullptr, nullptr);
    mm_bf16<64, 64, 2, 2, 2><<<dim3(32, 8), 256, 0, stream>>>(
        h, w2T + (size_t)i * DD * FF, FF, DD, f_b2 + (size_t)i * DD,
        xba, xa, xc, g2, be2);

    { float* t = xc; xc = xa; xa = t; }
    { __hip_bfloat16* t = xbc; xbc = xba; xba = t; }
  }

  fgemm_mfma<<<dim3(32, FG_KS), 256, 0, stream>>>(xbc, out_w, fpart);
  freduce<<<1000, 256, 0, stream>>>(fpart, out_b, out);
}